// Round 12
// baseline (411.754 us; speedup 1.0000x reference)
//
#include <hip/hip_runtime.h>
#include <stdint.h>

typedef unsigned short u16;
typedef __attribute__((ext_vector_type(4))) float f32x4;
typedef __attribute__((ext_vector_type(8))) short bf16x8;

static constexpr int S   = 2048;
static constexpr int DM  = 4096;  // model dim
static constexpr int NH  = 32;    // query heads
static constexpr int NKV = 8;     // kv heads
static constexpr int HD  = 128;   // head dim
static constexpr int LDQ = 5120;  // QK buffer row stride (Q 4096 | K 1024)

__device__ __forceinline__ u16 f2bf(float f) {
    union { float f; unsigned u; } v; v.f = f;
    return (u16)((v.u + 0x7FFFu + ((v.u >> 16) & 1u)) >> 16);
}
__device__ __forceinline__ float bf2f(u16 h) {
    union { unsigned u; float f; } v; v.u = ((unsigned)h) << 16;
    return v.f;
}
// pack 2 f32 -> 2 bf16 in one u32 (lo = first arg). T12 primitive.
__device__ __forceinline__ unsigned pk2bf(float lo, float hi) {
    unsigned r;
    asm("v_cvt_pk_bf16_f32 %0, %1, %2" : "=v"(r) : "v"(lo), "v"(hi));
    return r;
}

__device__ __forceinline__ void mfma16(f32x4& d, bf16x8 a, bf16x8 b) {
    asm("v_mfma_f32_16x16x32_bf16 %0, %1, %2, %0" : "+v"(d) : "v"(a), "v"(b));
}

// async global->LDS, 16B/lane. LDS base is wave-uniform; HW adds lane*16.
__device__ __forceinline__ void gload_lds16(const u16* g, u16* lds) {
    __builtin_amdgcn_global_load_lds((__attribute__((address_space(1))) void*)g,
                                     (__attribute__((address_space(3))) void*)lds,
                                     16, 0, 0);
}

// ---------------- fused fp32 -> bf16 convert: X | Wq | Wk | Wv | Wo ----------------
__global__ __launch_bounds__(256) void cvt_all(const float* __restrict__ X,
                                               const float* __restrict__ Wq,
                                               const float* __restrict__ Wk,
                                               const float* __restrict__ Wv,
                                               const float* __restrict__ Wo,
                                               u16* __restrict__ out) {
    const int n4 = 12582912;  // total float4 count
    int i = blockIdx.x * blockDim.x + threadIdx.x;
    int stride = gridDim.x * blockDim.x;
    for (; i < n4; i += stride) {
        float4 v;
        if (i < 2097152)       v = ((const float4*)X)[i];
        else if (i < 6291456)  v = ((const float4*)Wq)[i - 2097152];
        else if (i < 7340032)  v = ((const float4*)Wk)[i - 6291456];
        else if (i < 8388608)  v = ((const float4*)Wv)[i - 7340032];
        else                   v = ((const float4*)Wo)[i - 8388608];
        ushort4 o;
        o.x = f2bf(v.x); o.y = f2bf(v.y); o.z = f2bf(v.z); o.w = f2bf(v.w);
        ((ushort4*)out)[i] = o;
    }
}

// ---------------- RoPE cos/sin table ----------------
__global__ __launch_bounds__(256) void rope_table_kernel(float2* __restrict__ tbl) {
    int i = blockIdx.x * blockDim.x + threadIdx.x;
    if (i >= S * 64) return;
    int p = i >> 6, j = i & 63;
    float inv = powf(10000.0f, -(float)j / 64.0f);
    float a = (float)p * inv;
    tbl[i] = make_float2(cosf(a), sinf(a));
}

// ---------------- fused RoPE: Q heads (scale) + K heads, in-place on QKb ----------------
__global__ __launch_bounds__(256) void rope2_kernel(u16* __restrict__ X,
                                                    const float2* __restrict__ tbl,
                                                    float qscale) {
    int i = blockIdx.x * blockDim.x + threadIdx.x;
    const int total = S * 40 * 64;   // 32 Q heads + 8 K heads
    if (i >= total) return;
    int dd = i & 63;
    int t2 = i >> 6;
    int hh = t2 % 40;
    int s  = t2 / 40;
    size_t base;
    float scale;
    if (hh < 32) { base = (size_t)s * LDQ + hh * HD + dd;               scale = qscale; }
    else         { base = (size_t)s * LDQ + 4096 + (hh - 32) * HD + dd; scale = 1.0f;   }
    float x1 = bf2f(X[base]);
    float x2 = bf2f(X[base + 64]);
    float2 cs = tbl[(s << 6) + dd];
    X[base]      = f2bf((x1 * cs.x - x2 * cs.y) * scale);
    X[base + 64] = f2bf((x2 * cs.x + x1 * cs.y) * scale);
}

// ============== m97-structure 128x128 GEMM (4 waves, BK=64, 2-barrier) ==============
__global__ __launch_bounds__(256)
void gemm_bt(const u16* __restrict__ A, const u16* __restrict__ Bt,
             float* __restrict__ C, int M, int N, int K, int lda, int ldb, int ldc) {
    __shared__ u16 Al[128 * 64];
    __shared__ u16 Bl[128 * 64];
    const int t = threadIdx.x;
    const int w = t >> 6, l = t & 63;
    const int r16 = l & 15, g4 = l >> 4;
    const int m0 = blockIdx.y * 128, n0 = blockIdx.x * 128;
    const int wr = (w >> 1) * 64, wc = (w & 1) * 64;

    f32x4 acc[4][4];
#pragma unroll
    for (int i = 0; i < 4; ++i)
#pragma unroll
        for (int j = 0; j < 4; ++j) acc[i][j] = f32x4{0.f, 0.f, 0.f, 0.f};

    for (int kt = 0; kt < K; kt += 64) {
#pragma unroll
        for (int i = 0; i < 4; ++i) {
            int c = i * 256 + t;
            int r = c >> 3, s = (c & 7) ^ (r & 7);
            gload_lds16(A + (size_t)(m0 + r) * lda + kt + (s << 3),
                        Al + ((i * 256 + w * 64) << 3));
        }
#pragma unroll
        for (int i = 0; i < 4; ++i) {
            int c = i * 256 + t;
            int r = c >> 3, s = (c & 7) ^ (r & 7);
            gload_lds16(Bt + (size_t)(n0 + r) * ldb + kt + (s << 3),
                        Bl + ((i * 256 + w * 64) << 3));
        }
        asm volatile("s_waitcnt vmcnt(0)" ::: "memory");
        __syncthreads();

#pragma unroll
        for (int kk = 0; kk < 2; ++kk) {
            bf16x8 af[4], bfr[4];
#pragma unroll
            for (int mi = 0; mi < 4; ++mi) {
                int r = wr + mi * 16 + r16;
                af[mi] = *(const bf16x8*)((const char*)Al +
                          ((r * 128 + kk * 64 + g4 * 16) ^ ((r & 7) << 4)));
            }
#pragma unroll
            for (int ni = 0; ni < 4; ++ni) {
                int r = wc + ni * 16 + r16;
                bfr[ni] = *(const bf16x8*)((const char*)Bl +
                           ((r * 128 + kk * 64 + g4 * 16) ^ ((r & 7) << 4)));
            }
#pragma unroll
            for (int mi = 0; mi < 4; ++mi)
#pragma unroll
                for (int ni = 0; ni < 4; ++ni)
                    mfma16(acc[mi][ni], af[mi], bfr[ni]);
        }
        __syncthreads();
    }

    const int rb = g4 * 4;
#pragma unroll
    for (int mi = 0; mi < 4; ++mi)
#pragma unroll
        for (int ni = 0; ni < 4; ++ni) {
            const int n = n0 + wc + ni * 16 + r16;
            const int mbase = m0 + wr + mi * 16 + rb;
#pragma unroll
            for (int j = 0; j < 4; ++j)
                C[(size_t)(mbase + j) * ldc + n] = acc[mi][ni][j];
        }
}

// ---------------- fused QKV GEMM: X[2048][4096] * Wqkv[6144][4096]^T ----------------
__global__ __launch_bounds__(256)
void gemm_qkv(const u16* __restrict__ A, const u16* __restrict__ Bt,
              u16* __restrict__ Cqk, u16* __restrict__ Vt) {
    __shared__ u16 Al[128 * 64];
    __shared__ u16 Bl[128 * 64];
    const int t = threadIdx.x;
    const int w = t >> 6, l = t & 63;
    const int r16 = l & 15, g4 = l >> 4;
    const int m0 = blockIdx.y * 128, n0 = blockIdx.x * 128;
    const int wr = (w >> 1) * 64, wc = (w & 1) * 64;

    f32x4 acc[4][4];
#pragma unroll
    for (int i = 0; i < 4; ++i)
#pragma unroll
        for (int j = 0; j < 4; ++j) acc[i][j] = f32x4{0.f, 0.f, 0.f, 0.f};

    for (int kt = 0; kt < DM; kt += 64) {
#pragma unroll
        for (int i = 0; i < 4; ++i) {
            int c = i * 256 + t;
            int r = c >> 3, s = (c & 7) ^ (r & 7);
            gload_lds16(A + (size_t)(m0 + r) * DM + kt + (s << 3),
                        Al + ((i * 256 + w * 64) << 3));
        }
#pragma unroll
        for (int i = 0; i < 4; ++i) {
            int c = i * 256 + t;
            int r = c >> 3, s = (c & 7) ^ (r & 7);
            gload_lds16(Bt + (size_t)(n0 + r) * DM + kt + (s << 3),
                        Bl + ((i * 256 + w * 64) << 3));
        }
        asm volatile("s_waitcnt vmcnt(0)" ::: "memory");
        __syncthreads();

#pragma unroll
        for (int kk = 0; kk < 2; ++kk) {
            bf16x8 af[4], bfr[4];
#pragma unroll
            for (int mi = 0; mi < 4; ++mi) {
                int r = wr + mi * 16 + r16;
                af[mi] = *(const bf16x8*)((const char*)Al +
                          ((r * 128 + kk * 64 + g4 * 16) ^ ((r & 7) << 4)));
            }
#pragma unroll
            for (int ni = 0; ni < 4; ++ni) {
                int r = wc + ni * 16 + r16;
                bfr[ni] = *(const bf16x8*)((const char*)Bl +
                           ((r * 128 + kk * 64 + g4 * 16) ^ ((r & 7) << 4)));
            }
#pragma unroll
            for (int mi = 0; mi < 4; ++mi)
#pragma unroll
                for (int ni = 0; ni < 4; ++ni)
                    mfma16(acc[mi][ni], af[mi], bfr[ni]);
        }
        __syncthreads();
    }

    const int rb = g4 * 4;
    if (n0 < 5120) {  // Q|K region, row-major
#pragma unroll
        for (int mi = 0; mi < 4; ++mi)
#pragma unroll
            for (int ni = 0; ni < 4; ++ni) {
                const int n = n0 + wc + ni * 16 + r16;
                const int mbase = m0 + wr + mi * 16 + rb;
#pragma unroll
                for (int j = 0; j < 4; ++j)
                    Cqk[(size_t)(mbase + j) * LDQ + n] = f2bf(acc[mi][ni][j]);
            }
    } else {          // V region, transposed into Vt[1024][2048]
#pragma unroll
        for (int mi = 0; mi < 4; ++mi)
#pragma unroll
            for (int ni = 0; ni < 4; ++ni) {
                const int n = n0 + wc + ni * 16 + r16 - 5120;
                const int mbase = m0 + wr + mi * 16 + rb;
                ushort4 v4;
                v4.x = f2bf(acc[mi][ni][0]); v4.y = f2bf(acc[mi][ni][1]);
                v4.z = f2bf(acc[mi][ni][2]); v4.w = f2bf(acc[mi][ni][3]);
                *(ushort4*)&Vt[(size_t)n * S + mbase] = v4;
            }
    }
}

// ---------------- causal GQA flash attention (merged pairs, swapped QK^T, ----------------
// ---------------- pair-fused K reads ONLY) ----------------
// grid (16, 32): block p handles q-tiles p and 31-p off one KV stage (33 computes,
// balanced). Swapped QK^T (mfma(K,Q)): lane owns one q-row; softmax = in-lane tree
// + 2 shfl_xor (R10-verified). On paired iterations, ONE fused QK^T pass (each kf
// LDS read feeds both tiles, R8-verified safe) -- softmax+PV remain strictly
// sequential per tile with immediate P consumption in ONE shared per-wave P
// buffer (R6/R8/R10 pattern; no pf regs held across a softmax -> no spills).
// exp2-domain, defer-max, all LDS XOR-swizzled. LDS 72KB -> 2 blocks/CU.
__global__ __launch_bounds__(256, 2)
void attn_fwd(const u16* __restrict__ QK, const u16* __restrict__ Vt,
              u16* __restrict__ O) {
    __shared__ u16 Kl[2][64 * 128];   // 2 x 16KB
    __shared__ u16 Vl[2][128 * 64];   // 2 x 16KB
    __shared__ u16 Pl[4 * 1024];      // 8KB, per-wave 2KB (shared sequentially)

    const int t = threadIdx.x;
    const int w = t >> 6, l = t & 63;
    const int r16 = l & 15, g4 = l >> 4;
    const int h = blockIdx.y;
    const int kvh = h >> 2;
    const int p = blockIdx.x;                 // 0..15
    const int q0A = p * 64, q0B = (31 - p) * 64;
    const int ntA = p + 1, ntB = 32 - p;      // ntA <= ntB

    const u16* Kg = QK + 4096 + kvh * HD;
    const u16* Vg = Vt + (size_t)(kvh * HD) * S;
    u16* Pb = &Pl[w * 1024];

    bf16x8 qfA[4], qfB[4];
    {
        const u16* Qg = QK + h * HD;
        const size_t qrA = (size_t)(q0A + w * 16 + r16) * LDQ;
        const size_t qrB = (size_t)(q0B + w * 16 + r16) * LDQ;
#pragma unroll
        for (int kg = 0; kg < 4; ++kg) {
            qfA[kg] = *(const bf16x8*)&Qg[qrA + kg * 32 + g4 * 8];
            qfB[kg] = *(const bf16x8*)&Qg[qrB + kg * 32 + g4 * 8];
        }
    }

    f32x4 accA[8], accB[8];
    float mA = -3.0e38f, lA = 0.f, mB = -3.0e38f, lB = 0.f;
#pragma unroll
    for (int i = 0; i < 8; ++i) { accA[i] = f32x4{0,0,0,0}; accB[i] = f32x4{0,0,0,0}; }

    // stage KV tile tk into buffer b, source pre-swizzled (slot ^= row&7)
    auto stage = [&](int tk, int b) {
        const int kv0 = tk * 64;
#pragma unroll
        for (int i = 0; i < 4; ++i) {   // K: 64 rows x 256B (16 slots/row)
            int c = i * 256 + t;
            int r = c >> 4, s = (c & 15) ^ (r & 7);
            gload_lds16(Kg + (size_t)(kv0 + r) * LDQ + (s << 3),
                        &Kl[b][0] + ((i * 256 + w * 64) << 3));
        }
#pragma unroll
        for (int i = 0; i < 4; ++i) {   // Vt: 128 rows x 128B (8 slots/row)
            int c = i * 256 + t;
            int r = c >> 3, s = (c & 7) ^ (r & 7);
            gload_lds16(Vg + (size_t)r * S + kv0 + (s << 3),
                        &Vl[b][0] + ((i * 256 + w * 64) << 3));
        }
    };

    // R10-verified: softmax (swapped layout) + immediate PV, shared Pb
    auto soft_pv = [&](f32x4 (&sc)[4], float& mrun, float& lrun, f32x4 (&acco)[8],
                       int q0, int kv0, bool maskit, const u16* Vb) {
        const int qg = q0 + (w << 4) + r16;   // this lane's q row
        if (maskit) {
#pragma unroll
            for (int ni = 0; ni < 4; ++ni)
#pragma unroll
                for (int j = 0; j < 4; ++j)
                    if (kv0 + ni * 16 + g4 * 4 + j > qg) sc[ni][j] = -3.0e38f;
        }

        float v = fmaxf(fmaxf(fmaxf(sc[0][0], sc[0][1]), fmaxf(sc[0][2], sc[0][3])),
                        fmaxf(fmaxf(sc[1][0], sc[1][1]), fmaxf(sc[1][2], sc[1][3])));
        v = fmaxf(v, fmaxf(fmaxf(fmaxf(sc[2][0], sc[2][1]), fmaxf(sc[2][2], sc[2][3])),
                           fmaxf(fmaxf(sc[3][0], sc[3][1]), fmaxf(sc[3][2], sc[3][3]))));
        v = fmaxf(v, __shfl_xor(v, 16));
        v = fmaxf(v, __shfl_xor(v, 32));

        float facl = 1.f;
        if (__any(v > mrun + 11.5f)) {        // defer-max (T13)
            float nm = fmaxf(mrun, v);
            facl = exp2f(mrun - nm);
            mrun = nm;
            float fj[4];
#pragma unroll
            for (int j = 0; j < 4; ++j) fj[j] = __shfl(facl, g4 * 4 + j, 16);
#pragma unroll
            for (int i = 0; i < 8; ++i)
#pragma unroll
                for (int j = 0; j < 4; ++j) acco[i][j] *= fj[j];
        }
#pragma unroll
        for (int ni = 0; ni < 4; ++ni)
#pragma unroll
            for (int j = 0; j < 4; ++j) sc[ni][j] = exp2f(sc[ni][j] - mrun);

        float s2 = ((sc[0][0] + sc[0][1]) + (sc[0][2] + sc[0][3]))
                 + ((sc[1][0] + sc[1][1]) + (sc[1][2] + sc[1][3]))
                 + ((sc[2][0] + sc[2][1]) + (sc[2][2] + sc[2][3]))
                 + ((sc[3][0] + sc[3][1]) + (sc[3][2] + sc[3][3]));
        s2 += __shfl_xor(s2, 16);
        s2 += __shfl_xor(s2, 32);
        lrun = lrun * facl + s2;

        // P transposed -> per-wave LDS [q=r16][kv], 8 packed u32 stores
        {
            char* pp = (char*)Pb;
            const int swz = (r16 & 7) << 4;
            const int rowb = r16 * 128;
#pragma unroll
            for (int ti = 0; ti < 4; ++ti) {
                unsigned r01 = pk2bf(sc[ti][0], sc[ti][1]);
                unsigned r23 = pk2bf(sc[ti][2], sc[ti][3]);
                const int colb = (ti * 16 + g4 * 4) << 1;
                *(unsigned*)(pp + ((rowb + colb) ^ swz))     = r01;
                *(unsigned*)(pp + ((rowb + colb + 4) ^ swz)) = r23;
            }
        }
        asm volatile("s_waitcnt lgkmcnt(0)" ::: "memory");
        __builtin_amdgcn_sched_barrier(0);

        int pb0 = (r16 * 128 + g4 * 16) ^ ((r16 & 7) << 4);
        bf16x8 pf0 = *(const bf16x8*)((const char*)Pb + pb0);
        bf16x8 pf1 = *(const bf16x8*)((const char*)Pb + (pb0 ^ 64));
        __builtin_amdgcn_s_setprio(1);
#pragma unroll
        for (int ni = 0; ni < 8; ++ni) {
            int row = ni * 16 + r16;
            int bb = (row * 128 + g4 * 16) ^ ((row & 7) << 4);
            bf16x8 v0 = *(const bf16x8*)((const char*)Vb + bb);
            mfma16(acco[ni], pf0, v0);
            bf16x8 v1 = *(const bf16x8*)((const char*)Vb + (bb ^ 64));
            mfma16(acco[ni], pf1, v1);
        }
        __builtin_amdgcn_s_setprio(0);
        // pf reads retired before next soft_pv overwrites Pb (same-wave DS order +
        // lgkmcnt(0) at its P-write; R6/R8-proven pattern)
    };

    auto epilogue = [&](f32x4 (&acco)[8], float lrun, int q0) {
        float rlr = 1.0f / lrun;
        float rl[4];
#pragma unroll
        for (int j = 0; j < 4; ++j) rl[j] = __shfl(rlr, g4 * 4 + j, 16);
#pragma unroll
        for (int ni = 0; ni < 8; ++ni)
#pragma unroll
            for (int j = 0; j < 4; ++j) {
                const int qg = q0 + w * 16 + g4 * 4 + j;
                O[(size_t)qg * DM + h * HD + ni * 16 + r16] = f2bf(acco[ni][j] * rl[j]);
            }
    };

    stage(0, 0);
    asm volatile("s_waitcnt vmcnt(0)" ::: "memory");
    __syncthreads();
    int buf = 0;

    for (int tk = 0; tk < ntB; ++tk) {
        if (tk + 1 < ntB) stage(tk + 1, buf ^ 1);
        const int kv0 = tk * 64;
        const u16* Kb = &Kl[buf][0];
        const u16* Vb = &Vl[buf][0];

        if (tk < ntA) {
            // fused QK^T: each kf LDS read feeds both tiles (R8-verified)
            f32x4 scA[4], scB[4];
#pragma unroll
            for (int ni = 0; ni < 4; ++ni) { scA[ni] = f32x4{0,0,0,0}; scB[ni] = f32x4{0,0,0,0}; }
            __builtin_amdgcn_s_setprio(1);
#pragma unroll
            for (int kg = 0; kg < 4; ++kg) {
#pragma unroll
                for (int ni = 0; ni < 4; ++ni) {
                    int row = ni * 16 + r16;
                    int bb = (row * 256 + kg * 64 + g4 * 16) ^ ((row & 7) << 4);
                    bf16x8 kf = *(const bf16x8*)((const char*)Kb + bb);
                    mfma16(scB[ni], kf, qfB[kg]);
                    mfma16(scA[ni], kf, qfA[kg]);
                }
            }
            __builtin_amdgcn_s_setprio(0);

            soft_pv(scB, mB, lB, accB, q0B, kv0, tk == ntB - 1, Vb);
            soft_pv(scA, mA, lA, accA, q0A, kv0, tk == ntA - 1, Vb);
        } else {
            // single-tile (R10 path)
            f32x4 sc[4];
#pragma unroll
            for (int ni = 0; ni < 4; ++ni) sc[ni] = f32x4{0,0,0,0};
            __builtin_amdgcn_s_setprio(1);
#pragma unroll
            for (int kg = 0; kg < 4; ++kg) {
#pragma unroll
                for (int ni = 0; ni < 4; ++ni) {
                    int row = ni * 16 + r16;
                    int bb = (row * 256 + kg * 64 + g4 * 16) ^ ((row & 7) << 4);
                    bf16x8 kf = *(const bf16x8*)((const char*)Kb + bb);
                    mfma16(sc[ni], kf, qfB[kg]);
                }
            }
            __builtin_amdgcn_s_setprio(0);

            soft_pv(sc, mB, lB, accB, q0B, kv0, tk == ntB - 1, Vb);
        }

        asm volatile("s_waitcnt vmcnt(0)" ::: "memory");
        __syncthreads();
        buf ^= 1;
    }
    epilogue(accA, lA, q0A);
    epilogue(accB, lB, q0B);
}

// ---------------- launch ----------------
extern "C" void kernel_launch(void* const* d_in, const int* in_sizes, int n_in,
                              void* d_out, int out_size, void* d_ws, size_t ws_size,
                              hipStream_t stream) {
    const float* X  = (const float*)d_in[0];
    // d_in[1] = position_ids (arange(S) by construction)
    const float* Wq = (const float*)d_in[2];
    const float* Wk = (const float*)d_in[3];
    const float* Wv = (const float*)d_in[4];
    const float* Wo = (const float*)d_in[5];

    char* ws = (char*)d_ws;
    u16*    Xbf  = (u16*)(ws + 0);            // 2048x4096 bf16 = 16,777,216
    u16*    Wqkv = (u16*)(ws + 16777216);     // 6144x4096 bf16 = 50,331,648
    u16*    Wobf = (u16*)(ws + 67108864);     // 4096x4096 bf16 = 33,554,432
    u16*    QKb  = (u16*)(ws + 100663296);    // 2048x5120 bf16 = 20,971,520
    u16*    Vtbf = (u16*)(ws + 121634816);    // 1024x2048 bf16 =  4,194,304 (V^T)
    u16*    Obf  = (u16*)(ws + 125829120);    // 2048x4096 bf16 = 16,777,216
    float2* tbl  = (float2*)(ws + 142606336); // 2048x64 float2 =  1,048,576
    if (ws_size < 143654912ull) return;

    dim3 blk(256);

    cvt_all<<<2048, blk, 0, stream>>>(X, Wq, Wk, Wv, Wo, (u16*)ws);
    rope_table_kernel<<<(S * 64 + 255) / 256, blk, 0, stream>>>(tbl);

    // fused QKV projection: m97 128^2 + T2 swizzle, grid 48x16 = 768 blocks (3/CU)
    gemm_qkv<<<dim3(48, 16), blk, 0, stream>>>(Xbf, Wqkv, QKb, Vtbf);

    // fused RoPE over Q+K heads; Q folds in log2(e)*HD^-0.5 (exp2-domain softmax)
    rope2_kernel<<<(S * 40 * 64 + 255) / 256, blk, 0, stream>>>(
        QKb, tbl, 0.08838834764831845f * 1.4426950408889634f);

    // attention: swapped-QK^T softmax + pair-fused K reads, grid (16,32)
    attn_fwd<<<dim3(16, NH), blk, 0, stream>>>(QKb, Vtbf, Obf);

    // output projection -> fp32: m97 128^2, grid 32x16 = 512 blocks (2/CU)
    gemm_bt<<<dim3(DM / 128, S / 128), blk, 0, stream>>>(
        Obf, Wobf, (float*)d_out, S, DM, DM, DM, DM, DM);
}

// Round 13
// 337.625 us; speedup vs baseline: 1.2196x; 1.2196x over previous
//
#include <hip/hip_runtime.h>
#include <stdint.h>

typedef unsigned short u16;
typedef __attribute__((ext_vector_type(4))) float f32x4;
typedef __attribute__((ext_vector_type(8))) short bf16x8;

static constexpr int S   = 2048;
static constexpr int DM  = 4096;  // model dim
static constexpr int NH  = 32;    // query heads
static constexpr int NKV = 8;    // kv heads
static constexpr int HD  = 128;   // head dim
static constexpr int LDQ = 5120;  // QK buffer row stride (Q 4096 | K 1024)

__device__ __forceinline__ u16 f2bf(float f) {
    union { float f; unsigned u; } v; v.f = f;
    return (u16)((v.u + 0x7FFFu + ((v.u >> 16) & 1u)) >> 16);
}
__device__ __forceinline__ float bf2f(u16 h) {
    union { unsigned u; float f; } v; v.u = ((unsigned)h) << 16;
    return v.f;
}
// pack 2 f32 -> 2 bf16 in one u32 (lo = first arg). T12 primitive.
__device__ __forceinline__ unsigned pk2bf(float lo, float hi) {
    unsigned r;
    asm("v_cvt_pk_bf16_f32 %0, %1, %2" : "=v"(r) : "v"(lo), "v"(hi));
    return r;
}

__device__ __forceinline__ void mfma16(f32x4& d, bf16x8 a, bf16x8 b) {
    asm("v_mfma_f32_16x16x32_bf16 %0, %1, %2, %0" : "+v"(d) : "v"(a), "v"(b));
}

// async global->LDS, 16B/lane. LDS base is wave-uniform; HW adds lane*16.
__device__ __forceinline__ void gload_lds16(const u16* g, u16* lds) {
    __builtin_amdgcn_global_load_lds((__attribute__((address_space(1))) void*)g,
                                     (__attribute__((address_space(3))) void*)lds,
                                     16, 0, 0);
}

// ---------------- fused fp32 -> bf16 convert: X | Wq | Wk | Wv | Wo ----------------
__global__ __launch_bounds__(256) void cvt_all(const float* __restrict__ X,
                                               const float* __restrict__ Wq,
                                               const float* __restrict__ Wk,
                                               const float* __restrict__ Wv,
                                               const float* __restrict__ Wo,
                                               u16* __restrict__ out) {
    const int n4 = 12582912;  // total float4 count
    int i = blockIdx.x * blockDim.x + threadIdx.x;
    int stride = gridDim.x * blockDim.x;
    for (; i < n4; i += stride) {
        float4 v;
        if (i < 2097152)       v = ((const float4*)X)[i];
        else if (i < 6291456)  v = ((const float4*)Wq)[i - 2097152];
        else if (i < 7340032)  v = ((const float4*)Wk)[i - 6291456];
        else if (i < 8388608)  v = ((const float4*)Wv)[i - 7340032];
        else                   v = ((const float4*)Wo)[i - 8388608];
        ushort4 o;
        o.x = f2bf(v.x); o.y = f2bf(v.y); o.z = f2bf(v.z); o.w = f2bf(v.w);
        ((ushort4*)out)[i] = o;
    }
}

// ---------------- RoPE cos/sin table ----------------
__global__ __launch_bounds__(256) void rope_table_kernel(float2* __restrict__ tbl) {
    int i = blockIdx.x * blockDim.x + threadIdx.x;
    if (i >= S * 64) return;
    int p = i >> 6, j = i & 63;
    float inv = powf(10000.0f, -(float)j / 64.0f);
    float a = (float)p * inv;
    tbl[i] = make_float2(cosf(a), sinf(a));
}

// ---------------- fused RoPE: Q heads (scale) + K heads, in-place on QKb ----------------
__global__ __launch_bounds__(256) void rope2_kernel(u16* __restrict__ X,
                                                    const float2* __restrict__ tbl,
                                                    float qscale) {
    int i = blockIdx.x * blockDim.x + threadIdx.x;
    const int total = S * 40 * 64;   // 32 Q heads + 8 K heads
    if (i >= total) return;
    int dd = i & 63;
    int t2 = i >> 6;
    int hh = t2 % 40;
    int s  = t2 / 40;
    size_t base;
    float scale;
    if (hh < 32) { base = (size_t)s * LDQ + hh * HD + dd;               scale = qscale; }
    else         { base = (size_t)s * LDQ + 4096 + (hh - 32) * HD + dd; scale = 1.0f;   }
    float x1 = bf2f(X[base]);
    float x2 = bf2f(X[base + 64]);
    float2 cs = tbl[(s << 6) + dd];
    X[base]      = f2bf((x1 * cs.x - x2 * cs.y) * scale);
    X[base + 64] = f2bf((x2 * cs.x + x1 * cs.y) * scale);
}

// ============== m97-structure 128x128 GEMM (4 waves, BK=64, 2-barrier) ==============
__global__ __launch_bounds__(256)
void gemm_bt(const u16* __restrict__ A, const u16* __restrict__ Bt,
             float* __restrict__ C, int M, int N, int K, int lda, int ldb, int ldc) {
    __shared__ u16 Al[128 * 64];
    __shared__ u16 Bl[128 * 64];
    const int t = threadIdx.x;
    const int w = t >> 6, l = t & 63;
    const int r16 = l & 15, g4 = l >> 4;
    const int m0 = blockIdx.y * 128, n0 = blockIdx.x * 128;
    const int wr = (w >> 1) * 64, wc = (w & 1) * 64;

    f32x4 acc[4][4];
#pragma unroll
    for (int i = 0; i < 4; ++i)
#pragma unroll
        for (int j = 0; j < 4; ++j) acc[i][j] = f32x4{0.f, 0.f, 0.f, 0.f};

    for (int kt = 0; kt < K; kt += 64) {
#pragma unroll
        for (int i = 0; i < 4; ++i) {
            int c = i * 256 + t;
            int r = c >> 3, s = (c & 7) ^ (r & 7);
            gload_lds16(A + (size_t)(m0 + r) * lda + kt + (s << 3),
                        Al + ((i * 256 + w * 64) << 3));
        }
#pragma unroll
        for (int i = 0; i < 4; ++i) {
            int c = i * 256 + t;
            int r = c >> 3, s = (c & 7) ^ (r & 7);
            gload_lds16(Bt + (size_t)(n0 + r) * ldb + kt + (s << 3),
                        Bl + ((i * 256 + w * 64) << 3));
        }
        asm volatile("s_waitcnt vmcnt(0)" ::: "memory");
        __syncthreads();

#pragma unroll
        for (int kk = 0; kk < 2; ++kk) {
            bf16x8 af[4], bfr[4];
#pragma unroll
            for (int mi = 0; mi < 4; ++mi) {
                int r = wr + mi * 16 + r16;
                af[mi] = *(const bf16x8*)((const char*)Al +
                          ((r * 128 + kk * 64 + g4 * 16) ^ ((r & 7) << 4)));
            }
#pragma unroll
            for (int ni = 0; ni < 4; ++ni) {
                int r = wc + ni * 16 + r16;
                bfr[ni] = *(const bf16x8*)((const char*)Bl +
                           ((r * 128 + kk * 64 + g4 * 16) ^ ((r & 7) << 4)));
            }
#pragma unroll
            for (int mi = 0; mi < 4; ++mi)
#pragma unroll
                for (int ni = 0; ni < 4; ++ni)
                    mfma16(acc[mi][ni], af[mi], bfr[ni]);
        }
        __syncthreads();
    }

    const int rb = g4 * 4;
#pragma unroll
    for (int mi = 0; mi < 4; ++mi)
#pragma unroll
        for (int ni = 0; ni < 4; ++ni) {
            const int n = n0 + wc + ni * 16 + r16;
            const int mbase = m0 + wr + mi * 16 + rb;
#pragma unroll
            for (int j = 0; j < 4; ++j)
                C[(size_t)(mbase + j) * ldc + n] = acc[mi][ni][j];
        }
}

// ---------------- fused QKV GEMM: X[2048][4096] * Wqkv[6144][4096]^T ----------------
__global__ __launch_bounds__(256)
void gemm_qkv(const u16* __restrict__ A, const u16* __restrict__ Bt,
              u16* __restrict__ Cqk, u16* __restrict__ Vt) {
    __shared__ u16 Al[128 * 64];
    __shared__ u16 Bl[128 * 64];
    const int t = threadIdx.x;
    const int w = t >> 6, l = t & 63;
    const int r16 = l & 15, g4 = l >> 4;
    const int m0 = blockIdx.y * 128, n0 = blockIdx.x * 128;
    const int wr = (w >> 1) * 64, wc = (w & 1) * 64;

    f32x4 acc[4][4];
#pragma unroll
    for (int i = 0; i < 4; ++i)
#pragma unroll
        for (int j = 0; j < 4; ++j) acc[i][j] = f32x4{0.f, 0.f, 0.f, 0.f};

    for (int kt = 0; kt < DM; kt += 64) {
#pragma unroll
        for (int i = 0; i < 4; ++i) {
            int c = i * 256 + t;
            int r = c >> 3, s = (c & 7) ^ (r & 7);
            gload_lds16(A + (size_t)(m0 + r) * DM + kt + (s << 3),
                        Al + ((i * 256 + w * 64) << 3));
        }
#pragma unroll
        for (int i = 0; i < 4; ++i) {
            int c = i * 256 + t;
            int r = c >> 3, s = (c & 7) ^ (r & 7);
            gload_lds16(Bt + (size_t)(n0 + r) * DM + kt + (s << 3),
                        Bl + ((i * 256 + w * 64) << 3));
        }
        asm volatile("s_waitcnt vmcnt(0)" ::: "memory");
        __syncthreads();

#pragma unroll
        for (int kk = 0; kk < 2; ++kk) {
            bf16x8 af[4], bfr[4];
#pragma unroll
            for (int mi = 0; mi < 4; ++mi) {
                int r = wr + mi * 16 + r16;
                af[mi] = *(const bf16x8*)((const char*)Al +
                          ((r * 128 + kk * 64 + g4 * 16) ^ ((r & 7) << 4)));
            }
#pragma unroll
            for (int ni = 0; ni < 4; ++ni) {
                int r = wc + ni * 16 + r16;
                bfr[ni] = *(const bf16x8*)((const char*)Bl +
                           ((r * 128 + kk * 64 + g4 * 16) ^ ((r & 7) << 4)));
            }
#pragma unroll
            for (int mi = 0; mi < 4; ++mi)
#pragma unroll
                for (int ni = 0; ni < 4; ++ni)
                    mfma16(acc[mi][ni], af[mi], bfr[ni]);
        }
        __syncthreads();
    }

    const int rb = g4 * 4;
    if (n0 < 5120) {  // Q|K region, row-major
#pragma unroll
        for (int mi = 0; mi < 4; ++mi)
#pragma unroll
            for (int ni = 0; ni < 4; ++ni) {
                const int n = n0 + wc + ni * 16 + r16;
                const int mbase = m0 + wr + mi * 16 + rb;
#pragma unroll
                for (int j = 0; j < 4; ++j)
                    Cqk[(size_t)(mbase + j) * LDQ + n] = f2bf(acc[mi][ni][j]);
            }
    } else {          // V region, transposed into Vt[1024][2048]
#pragma unroll
        for (int mi = 0; mi < 4; ++mi)
#pragma unroll
            for (int ni = 0; ni < 4; ++ni) {
                const int n = n0 + wc + ni * 16 + r16 - 5120;
                const int mbase = m0 + wr + mi * 16 + rb;
                ushort4 v4;
                v4.x = f2bf(acc[mi][ni][0]); v4.y = f2bf(acc[mi][ni][1]);
                v4.z = f2bf(acc[mi][ni][2]); v4.w = f2bf(acc[mi][ni][3]);
                *(ushort4*)&Vt[(size_t)n * S + mbase] = v4;
            }
    }
}

// ---------------- causal GQA flash attention (4 waves, merged pairs, swapped QK^T) ----------------
// grid (16, 32): block p handles q-tiles p and 31-p; one KV stage serves both
// computes (33 tile-computes per block, balanced). SWAPPED QK^T: mfma(K, Q) gives
// D[kv][q] -- each lane owns ONE q-row (q = lane&15) with all 64 kv in registers,
// so row max/sum = in-lane tree + 2 shfl_xor (vs 32 shuffles). mrun/lrun are
// per-lane scalars; rescale factors broadcast by 4 width-16 shuffles on grow only.
// P written transposed into the SAME per-wave [q][kv] LDS buffer the R6 PV path
// consumes. exp2-domain softmax, defer-max. All LDS XOR-swizzled. 72KB LDS.
__global__ __launch_bounds__(256, 2)
void attn_fwd(const u16* __restrict__ QK, const u16* __restrict__ Vt,
              u16* __restrict__ O) {
    __shared__ u16 Kl[2][64 * 128];   // 2 x 16KB
    __shared__ u16 Vl[2][128 * 64];   // 2 x 16KB
    __shared__ u16 Pl[4 * 1024];      // 8KB, per-wave 2KB

    const int t = threadIdx.x;
    const int w = t >> 6, l = t & 63;
    const int r16 = l & 15, g4 = l >> 4;
    const int h = blockIdx.y;
    const int kvh = h >> 2;
    const int p = blockIdx.x;                 // 0..15
    const int q0A = p * 64, q0B = (31 - p) * 64;
    const int ntA = p + 1, ntB = 32 - p;      // ntA <= ntB

    const u16* Kg = QK + 4096 + kvh * HD;
    const u16* Vg = Vt + (size_t)(kvh * HD) * S;
    u16* Pb = &Pl[w * 1024];

    bf16x8 qfA[4], qfB[4];
    {
        const u16* Qg = QK + h * HD;
        const size_t qrA = (size_t)(q0A + w * 16 + r16) * LDQ;
        const size_t qrB = (size_t)(q0B + w * 16 + r16) * LDQ;
#pragma unroll
        for (int kg = 0; kg < 4; ++kg) {
            qfA[kg] = *(const bf16x8*)&Qg[qrA + kg * 32 + g4 * 8];
            qfB[kg] = *(const bf16x8*)&Qg[qrB + kg * 32 + g4 * 8];
        }
    }

    f32x4 accA[8], accB[8];
    float mA = -3.0e38f, lA = 0.f, mB = -3.0e38f, lB = 0.f;
#pragma unroll
    for (int i = 0; i < 8; ++i) { accA[i] = f32x4{0,0,0,0}; accB[i] = f32x4{0,0,0,0}; }

    // stage KV tile tk into buffer b, source pre-swizzled (slot ^= row&7)
    auto stage = [&](int tk, int b) {
        const int kv0 = tk * 64;
#pragma unroll
        for (int i = 0; i < 4; ++i) {   // K: 64 rows x 256B (16 slots/row)
            int c = i * 256 + t;
            int r = c >> 4, s = (c & 15) ^ (r & 7);
            gload_lds16(Kg + (size_t)(kv0 + r) * LDQ + (s << 3),
                        &Kl[b][0] + ((i * 256 + w * 64) << 3));
        }
#pragma unroll
        for (int i = 0; i < 4; ++i) {   // Vt: 128 rows x 128B (8 slots/row)
            int c = i * 256 + t;
            int r = c >> 3, s = (c & 7) ^ (r & 7);
            gload_lds16(Vg + (size_t)r * S + kv0 + (s << 3),
                        &Vl[b][0] + ((i * 256 + w * 64) << 3));
        }
    };

    auto compute = [&](f32x4 (&acco)[8], float& mrun, float& lrun,
                       const bf16x8 (&qf)[4], int q0, int tk, bool maskit, int b) {
        const int kv0 = tk * 64;
        const u16* Kb = &Kl[b][0];
        const u16* Vb = &Vl[b][0];

        // swapped QK^T: D[kv][q]; lane owns q = r16, kv = ni*16 + g4*4 + j
        f32x4 sc[4];
#pragma unroll
        for (int ni = 0; ni < 4; ++ni) sc[ni] = f32x4{0,0,0,0};
        __builtin_amdgcn_s_setprio(1);
#pragma unroll
        for (int kg = 0; kg < 4; ++kg) {
#pragma unroll
            for (int ni = 0; ni < 4; ++ni) {
                int row = ni * 16 + r16;
                int bb = (row * 256 + kg * 64 + g4 * 16) ^ ((row & 7) << 4);
                bf16x8 kf = *(const bf16x8*)((const char*)Kb + bb);
                mfma16(sc[ni], kf, qf[kg]);   // K as A-operand, Q as B-operand
            }
        }
        __builtin_amdgcn_s_setprio(0);

        const int qg = q0 + (w << 4) + r16;   // this lane's q row
        if (maskit) {
#pragma unroll
            for (int ni = 0; ni < 4; ++ni)
#pragma unroll
                for (int j = 0; j < 4; ++j)
                    if (kv0 + ni * 16 + g4 * 4 + j > qg) sc[ni][j] = -3.0e38f;
        }

        // row max: in-lane tree over 16 regs + 2 shfl_xor
        float v = fmaxf(fmaxf(fmaxf(sc[0][0], sc[0][1]), fmaxf(sc[0][2], sc[0][3])),
                        fmaxf(fmaxf(sc[1][0], sc[1][1]), fmaxf(sc[1][2], sc[1][3])));
        v = fmaxf(v, fmaxf(fmaxf(fmaxf(sc[2][0], sc[2][1]), fmaxf(sc[2][2], sc[2][3])),
                           fmaxf(fmaxf(sc[3][0], sc[3][1]), fmaxf(sc[3][2], sc[3][3]))));
        v = fmaxf(v, __shfl_xor(v, 16));
        v = fmaxf(v, __shfl_xor(v, 32));

        float facl = 1.f;
        if (__any(v > mrun + 11.5f)) {        // defer-max (T13)
            float nm = fmaxf(mrun, v);
            facl = exp2f(mrun - nm);
            mrun = nm;
            float fj[4];
#pragma unroll
            for (int j = 0; j < 4; ++j) fj[j] = __shfl(facl, g4 * 4 + j, 16);
#pragma unroll
            for (int i = 0; i < 8; ++i)
#pragma unroll
                for (int j = 0; j < 4; ++j) acco[i][j] *= fj[j];
        }
#pragma unroll
        for (int ni = 0; ni < 4; ++ni)
#pragma unroll
            for (int j = 0; j < 4; ++j) sc[ni][j] = exp2f(sc[ni][j] - mrun);

        // row sum: in-lane 15 adds + 2 shfl_xor
        float s2 = ((sc[0][0] + sc[0][1]) + (sc[0][2] + sc[0][3]))
                 + ((sc[1][0] + sc[1][1]) + (sc[1][2] + sc[1][3]))
                 + ((sc[2][0] + sc[2][1]) + (sc[2][2] + sc[2][3]))
                 + ((sc[3][0] + sc[3][1]) + (sc[3][2] + sc[3][3]));
        s2 += __shfl_xor(s2, 16);
        s2 += __shfl_xor(s2, 32);
        lrun = lrun * facl + s2;

        // P transposed -> per-wave LDS [q=r16][kv], 8 packed u32 stores
        {
            char* pp = (char*)Pb;
            const int swz = (r16 & 7) << 4;
            const int rowb = r16 * 128;
#pragma unroll
            for (int ti = 0; ti < 4; ++ti) {
                unsigned r01 = pk2bf(sc[ti][0], sc[ti][1]);
                unsigned r23 = pk2bf(sc[ti][2], sc[ti][3]);
                const int colb = (ti * 16 + g4 * 4) << 1;
                *(unsigned*)(pp + ((rowb + colb) ^ swz))     = r01;
                *(unsigned*)(pp + ((rowb + colb + 4) ^ swz)) = r23;
            }
        }
        asm volatile("s_waitcnt lgkmcnt(0)" ::: "memory");
        __builtin_amdgcn_sched_barrier(0);

        // PV (unchanged R6 path): A = P[q][kv] frags, B = V^T frags
        int pb0 = (r16 * 128 + g4 * 16) ^ ((r16 & 7) << 4);
        bf16x8 pf0 = *(const bf16x8*)((const char*)Pb + pb0);
        bf16x8 pf1 = *(const bf16x8*)((const char*)Pb + (pb0 ^ 64));
        __builtin_amdgcn_s_setprio(1);
#pragma unroll
        for (int ni = 0; ni < 8; ++ni) {
            int row = ni * 16 + r16;
            int bb = (row * 128 + g4 * 16) ^ ((row & 7) << 4);
            bf16x8 v0 = *(const bf16x8*)((const char*)Vb + bb);
            mfma16(acco[ni], pf0, v0);
            bf16x8 v1 = *(const bf16x8*)((const char*)Vb + (bb ^ 64));
            mfma16(acco[ni], pf1, v1);
        }
        __builtin_amdgcn_s_setprio(0);
    };

    auto epilogue = [&](f32x4 (&acco)[8], float lrun, int q0) {
        float rlr = 1.0f / lrun;
        float rl[4];
#pragma unroll
        for (int j = 0; j < 4; ++j) rl[j] = __shfl(rlr, g4 * 4 + j, 16);
#pragma unroll
        for (int ni = 0; ni < 8; ++ni)
#pragma unroll
            for (int j = 0; j < 4; ++j) {
                const int qg = q0 + w * 16 + g4 * 4 + j;
                O[(size_t)qg * DM + h * HD + ni * 16 + r16] = f2bf(acco[ni][j] * rl[j]);
            }
    };

    stage(0, 0);
    asm volatile("s_waitcnt vmcnt(0)" ::: "memory");
    __syncthreads();
    int buf = 0;

    for (int tk = 0; tk < ntB; ++tk) {
        if (tk + 1 < ntB) stage(tk + 1, buf ^ 1);
        compute(accB, mB, lB, qfB, q0B, tk, tk == ntB - 1, buf);
        if (tk < ntA) compute(accA, mA, lA, qfA, q0A, tk, tk == ntA - 1, buf);
        asm volatile("s_waitcnt vmcnt(0)" ::: "memory");
        __syncthreads();
        buf ^= 1;
    }
    epilogue(accA, lA, q0A);
    epilogue(accB, lB, q0B);
}

// ---------------- launch ----------------
extern "C" void kernel_launch(void* const* d_in, const int* in_sizes, int n_in,
                              void* d_out, int out_size, void* d_ws, size_t ws_size,
                              hipStream_t stream) {
    const float* X  = (const float*)d_in[0];
    // d_in[1] = position_ids (arange(S) by construction)
    const float* Wq = (const float*)d_in[2];
    const float* Wk = (const float*)d_in[3];
    const float* Wv = (const float*)d_in[4];
    const float* Wo = (const float*)d_in[5];

    char* ws = (char*)d_ws;
    u16*    Xbf  = (u16*)(ws + 0);            // 2048x4096 bf16 = 16,777,216
    u16*    Wqkv = (u16*)(ws + 16777216);     // 6144x4096 bf16 = 50,331,648
    u16*    Wobf = (u16*)(ws + 67108864);     // 4096x4096 bf16 = 33,554,432
    u16*    QKb  = (u16*)(ws + 100663296);    // 2048x5120 bf16 = 20,971,520
    u16*    Vtbf = (u16*)(ws + 121634816);    // 1024x2048 bf16 =  4,194,304 (V^T)
    u16*    Obf  = (u16*)(ws + 125829120);    // 2048x4096 bf16 = 16,777,216
    float2* tbl  = (float2*)(ws + 142606336); // 2048x64 float2 =  1,048,576
    if (ws_size < 143654912ull) return;

    dim3 blk(256);

    cvt_all<<<2048, blk, 0, stream>>>(X, Wq, Wk, Wv, Wo, (u16*)ws);
    rope_table_kernel<<<(S * 64 + 255) / 256, blk, 0, stream>>>(tbl);

    // fused QKV projection: m97 128^2 + T2 swizzle, grid 48x16 = 768 blocks (3/CU)
    gemm_qkv<<<dim3(48, 16), blk, 0, stream>>>(Xbf, Wqkv, QKb, Vtbf);

    // fused RoPE over Q+K heads; Q folds in log2(e)*HD^-0.5 (exp2-domain softmax)
    rope2_kernel<<<(S * 40 * 64 + 255) / 256, blk, 0, stream>>>(
        QKb, tbl, 0.08838834764831845f * 1.4426950408889634f);

    // attention: swapped-QK^T in-register softmax, merged pairs, grid (16,32)
    attn_fwd<<<dim3(16, NH), blk, 0, stream>>>(QKb, Vtbf, Obf);

    // output projection -> fp32: m97 128^2, grid 32x16 = 512 blocks (2/CU)
    gemm_bt<<<dim3(DM / 128, S / 128), blk, 0, stream>>>(
        Obf, Wobf, (float*)d_out, S, DM, DM, DM, DM, DM);
}

// Round 14
// 332.814 us; speedup vs baseline: 1.2372x; 1.0145x over previous
//
#include <hip/hip_runtime.h>
#include <stdint.h>

typedef unsigned short u16;
typedef __attribute__((ext_vector_type(4))) float f32x4;
typedef __attribute__((ext_vector_type(8))) short bf16x8;

static constexpr int S   = 2048;
static constexpr int DM  = 4096;  // model dim
static constexpr int NH  = 32;    // query heads
static constexpr int NKV = 8;     // kv heads
static constexpr int HD  = 128;   // head dim
static constexpr int LDQ = 5120;  // QK buffer row stride (Q 4096 | K 1024)

__device__ __forceinline__ u16 f2bf(float f) {
    union { float f; unsigned u; } v; v.f = f;
    return (u16)((v.u + 0x7FFFu + ((v.u >> 16) & 1u)) >> 16);
}
__device__ __forceinline__ float bf2f(u16 h) {
    union { unsigned u; float f; } v; v.u = ((unsigned)h) << 16;
    return v.f;
}
// pack 2 f32 -> 2 bf16 in one u32 (lo = first arg). T12 primitive.
__device__ __forceinline__ unsigned pk2bf(float lo, float hi) {
    unsigned r;
    asm("v_cvt_pk_bf16_f32 %0, %1, %2" : "=v"(r) : "v"(lo), "v"(hi));
    return r;
}

__device__ __forceinline__ void mfma16(f32x4& d, bf16x8 a, bf16x8 b) {
    asm("v_mfma_f32_16x16x32_bf16 %0, %1, %2, %0" : "+v"(d) : "v"(a), "v"(b));
}

// async global->LDS, 16B/lane. LDS base is wave-uniform; HW adds lane*16.
__device__ __forceinline__ void gload_lds16(const u16* g, u16* lds) {
    __builtin_amdgcn_global_load_lds((__attribute__((address_space(1))) void*)g,
                                     (__attribute__((address_space(3))) void*)lds,
                                     16, 0, 0);
}

// ---------------- fused fp32 -> bf16 convert: X | Wq | Wk | Wv | Wo ----------------
__global__ __launch_bounds__(256) void cvt_all(const float* __restrict__ X,
                                               const float* __restrict__ Wq,
                                               const float* __restrict__ Wk,
                                               const float* __restrict__ Wv,
                                               const float* __restrict__ Wo,
                                               u16* __restrict__ out) {
    const int n4 = 12582912;  // total float4 count
    int i = blockIdx.x * blockDim.x + threadIdx.x;
    int stride = gridDim.x * blockDim.x;
    for (; i < n4; i += stride) {
        float4 v;
        if (i < 2097152)       v = ((const float4*)X)[i];
        else if (i < 6291456)  v = ((const float4*)Wq)[i - 2097152];
        else if (i < 7340032)  v = ((const float4*)Wk)[i - 6291456];
        else if (i < 8388608)  v = ((const float4*)Wv)[i - 7340032];
        else                   v = ((const float4*)Wo)[i - 8388608];
        ushort4 o;
        o.x = f2bf(v.x); o.y = f2bf(v.y); o.z = f2bf(v.z); o.w = f2bf(v.w);
        ((ushort4*)out)[i] = o;
    }
}

// ---------------- split-K reduce: out = a + b (f32, float4) ----------------
__global__ __launch_bounds__(256) void add2_kernel(const float* __restrict__ a,
                                                   const float* __restrict__ b,
                                                   float* __restrict__ o, int n4) {
    int i = blockIdx.x * blockDim.x + threadIdx.x;
    int st = gridDim.x * blockDim.x;
    for (; i < n4; i += st) {
        float4 x = ((const float4*)a)[i];
        float4 y = ((const float4*)b)[i];
        x.x += y.x; x.y += y.y; x.z += y.z; x.w += y.w;
        ((float4*)o)[i] = x;
    }
}

// ---------------- RoPE cos/sin table ----------------
__global__ __launch_bounds__(256) void rope_table_kernel(float2* __restrict__ tbl) {
    int i = blockIdx.x * blockDim.x + threadIdx.x;
    if (i >= S * 64) return;
    int p = i >> 6, j = i & 63;
    float inv = powf(10000.0f, -(float)j / 64.0f);
    float a = (float)p * inv;
    tbl[i] = make_float2(cosf(a), sinf(a));
}

// ---------------- fused RoPE: Q heads (scale) + K heads, in-place on QKb ----------------
__global__ __launch_bounds__(256) void rope2_kernel(u16* __restrict__ X,
                                                    const float2* __restrict__ tbl,
                                                    float qscale) {
    int i = blockIdx.x * blockDim.x + threadIdx.x;
    const int total = S * 40 * 64;   // 32 Q heads + 8 K heads
    if (i >= total) return;
    int dd = i & 63;
    int t2 = i >> 6;
    int hh = t2 % 40;
    int s  = t2 / 40;
    size_t base;
    float scale;
    if (hh < 32) { base = (size_t)s * LDQ + hh * HD + dd;               scale = qscale; }
    else         { base = (size_t)s * LDQ + 4096 + (hh - 32) * HD + dd; scale = 1.0f;   }
    float x1 = bf2f(X[base]);
    float x2 = bf2f(X[base + 64]);
    float2 cs = tbl[(s << 6) + dd];
    X[base]      = f2bf((x1 * cs.x - x2 * cs.y) * scale);
    X[base + 64] = f2bf((x2 * cs.x + x1 * cs.y) * scale);
}

// ============== m97-structure 128x128 GEMM (4 waves, BK=64, 2-barrier) ==============
// SPLITK>1: blockIdx.z picks a K-slice of length K/SPLITK; output written to
// C + z*M*ldc (f32 partials; reduce with add2_kernel).
template<int SPLITK>
__global__ __launch_bounds__(256)
void gemm_bt(const u16* __restrict__ A, const u16* __restrict__ Bt,
             float* __restrict__ C, int M, int N, int K, int lda, int ldb, int ldc) {
    __shared__ u16 Al[128 * 64];
    __shared__ u16 Bl[128 * 64];
    const int t = threadIdx.x;
    const int w = t >> 6, l = t & 63;
    const int r16 = l & 15, g4 = l >> 4;
    const int m0 = blockIdx.y * 128, n0 = blockIdx.x * 128;
    const int wr = (w >> 1) * 64, wc = (w & 1) * 64;

    const int Kper = K / SPLITK;
    const int k0 = (SPLITK > 1) ? blockIdx.z * Kper : 0;
    if (SPLITK > 1) C += (size_t)blockIdx.z * M * ldc;

    f32x4 acc[4][4];
#pragma unroll
    for (int i = 0; i < 4; ++i)
#pragma unroll
        for (int j = 0; j < 4; ++j) acc[i][j] = f32x4{0.f, 0.f, 0.f, 0.f};

    for (int kt = k0; kt < k0 + Kper; kt += 64) {
#pragma unroll
        for (int i = 0; i < 4; ++i) {
            int c = i * 256 + t;
            int r = c >> 3, s = (c & 7) ^ (r & 7);
            gload_lds16(A + (size_t)(m0 + r) * lda + kt + (s << 3),
                        Al + ((i * 256 + w * 64) << 3));
        }
#pragma unroll
        for (int i = 0; i < 4; ++i) {
            int c = i * 256 + t;
            int r = c >> 3, s = (c & 7) ^ (r & 7);
            gload_lds16(Bt + (size_t)(n0 + r) * ldb + kt + (s << 3),
                        Bl + ((i * 256 + w * 64) << 3));
        }
        asm volatile("s_waitcnt vmcnt(0)" ::: "memory");
        __syncthreads();

#pragma unroll
        for (int kk = 0; kk < 2; ++kk) {
            bf16x8 af[4], bfr[4];
#pragma unroll
            for (int mi = 0; mi < 4; ++mi) {
                int r = wr + mi * 16 + r16;
                af[mi] = *(const bf16x8*)((const char*)Al +
                          ((r * 128 + kk * 64 + g4 * 16) ^ ((r & 7) << 4)));
            }
#pragma unroll
            for (int ni = 0; ni < 4; ++ni) {
                int r = wc + ni * 16 + r16;
                bfr[ni] = *(const bf16x8*)((const char*)Bl +
                           ((r * 128 + kk * 64 + g4 * 16) ^ ((r & 7) << 4)));
            }
#pragma unroll
            for (int mi = 0; mi < 4; ++mi)
#pragma unroll
                for (int ni = 0; ni < 4; ++ni)
                    mfma16(acc[mi][ni], af[mi], bfr[ni]);
        }
        __syncthreads();
    }

    const int rb = g4 * 4;
#pragma unroll
    for (int mi = 0; mi < 4; ++mi)
#pragma unroll
        for (int ni = 0; ni < 4; ++ni) {
            const int n = n0 + wc + ni * 16 + r16;
            const int mbase = m0 + wr + mi * 16 + rb;
#pragma unroll
            for (int j = 0; j < 4; ++j)
                C[(size_t)(mbase + j) * ldc + n] = acc[mi][ni][j];
        }
}

// ---------------- fused QKV GEMM: X[2048][4096] * Wqkv[6144][4096]^T ----------------
__global__ __launch_bounds__(256)
void gemm_qkv(const u16* __restrict__ A, const u16* __restrict__ Bt,
              u16* __restrict__ Cqk, u16* __restrict__ Vt) {
    __shared__ u16 Al[128 * 64];
    __shared__ u16 Bl[128 * 64];
    const int t = threadIdx.x;
    const int w = t >> 6, l = t & 63;
    const int r16 = l & 15, g4 = l >> 4;
    const int m0 = blockIdx.y * 128, n0 = blockIdx.x * 128;
    const int wr = (w >> 1) * 64, wc = (w & 1) * 64;

    f32x4 acc[4][4];
#pragma unroll
    for (int i = 0; i < 4; ++i)
#pragma unroll
        for (int j = 0; j < 4; ++j) acc[i][j] = f32x4{0.f, 0.f, 0.f, 0.f};

    for (int kt = 0; kt < DM; kt += 64) {
#pragma unroll
        for (int i = 0; i < 4; ++i) {
            int c = i * 256 + t;
            int r = c >> 3, s = (c & 7) ^ (r & 7);
            gload_lds16(A + (size_t)(m0 + r) * DM + kt + (s << 3),
                        Al + ((i * 256 + w * 64) << 3));
        }
#pragma unroll
        for (int i = 0; i < 4; ++i) {
            int c = i * 256 + t;
            int r = c >> 3, s = (c & 7) ^ (r & 7);
            gload_lds16(Bt + (size_t)(n0 + r) * DM + kt + (s << 3),
                        Bl + ((i * 256 + w * 64) << 3));
        }
        asm volatile("s_waitcnt vmcnt(0)" ::: "memory");
        __syncthreads();

#pragma unroll
        for (int kk = 0; kk < 2; ++kk) {
            bf16x8 af[4], bfr[4];
#pragma unroll
            for (int mi = 0; mi < 4; ++mi) {
                int r = wr + mi * 16 + r16;
                af[mi] = *(const bf16x8*)((const char*)Al +
                          ((r * 128 + kk * 64 + g4 * 16) ^ ((r & 7) << 4)));
            }
#pragma unroll
            for (int ni = 0; ni < 4; ++ni) {
                int r = wc + ni * 16 + r16;
                bfr[ni] = *(const bf16x8*)((const char*)Bl +
                           ((r * 128 + kk * 64 + g4 * 16) ^ ((r & 7) << 4)));
            }
#pragma unroll
            for (int mi = 0; mi < 4; ++mi)
#pragma unroll
                for (int ni = 0; ni < 4; ++ni)
                    mfma16(acc[mi][ni], af[mi], bfr[ni]);
        }
        __syncthreads();
    }

    const int rb = g4 * 4;
    if (n0 < 5120) {  // Q|K region, row-major
#pragma unroll
        for (int mi = 0; mi < 4; ++mi)
#pragma unroll
            for (int ni = 0; ni < 4; ++ni) {
                const int n = n0 + wc + ni * 16 + r16;
                const int mbase = m0 + wr + mi * 16 + rb;
#pragma unroll
                for (int j = 0; j < 4; ++j)
                    Cqk[(size_t)(mbase + j) * LDQ + n] = f2bf(acc[mi][ni][j]);
            }
    } else {          // V region, transposed into Vt[1024][2048]
#pragma unroll
        for (int mi = 0; mi < 4; ++mi)
#pragma unroll
            for (int ni = 0; ni < 4; ++ni) {
                const int n = n0 + wc + ni * 16 + r16 - 5120;
                const int mbase = m0 + wr + mi * 16 + rb;
                ushort4 v4;
                v4.x = f2bf(acc[mi][ni][0]); v4.y = f2bf(acc[mi][ni][1]);
                v4.z = f2bf(acc[mi][ni][2]); v4.w = f2bf(acc[mi][ni][3]);
                *(ushort4*)&Vt[(size_t)n * S + mbase] = v4;
            }
    }
}

// ---------------- causal GQA flash attention (4 waves, merged pairs, swapped QK^T) ----------------
// grid (16, 32): block p handles q-tiles p and 31-p; one KV stage serves both
// computes (33 tile-computes per block, balanced). SWAPPED QK^T: mfma(K, Q) gives
// D[kv][q] -- each lane owns ONE q-row (q = lane&15) with all 64 kv in registers,
// so row max/sum = in-lane tree + 2 shfl_xor (vs 32 shuffles). mrun/lrun are
// per-lane scalars; rescale factors broadcast by 4 width-16 shuffles on grow only.
// P written transposed into the SAME per-wave [q][kv] LDS buffer the R6 PV path
// consumes. exp2-domain softmax, defer-max. All LDS XOR-swizzled. 72KB LDS.
__global__ __launch_bounds__(256, 2)
void attn_fwd(const u16* __restrict__ QK, const u16* __restrict__ Vt,
              u16* __restrict__ O) {
    __shared__ u16 Kl[2][64 * 128];   // 2 x 16KB
    __shared__ u16 Vl[2][128 * 64];   // 2 x 16KB
    __shared__ u16 Pl[4 * 1024];      // 8KB, per-wave 2KB

    const int t = threadIdx.x;
    const int w = t >> 6, l = t & 63;
    const int r16 = l & 15, g4 = l >> 4;
    const int h = blockIdx.y;
    const int kvh = h >> 2;
    const int p = blockIdx.x;                 // 0..15
    const int q0A = p * 64, q0B = (31 - p) * 64;
    const int ntA = p + 1, ntB = 32 - p;      // ntA <= ntB

    const u16* Kg = QK + 4096 + kvh * HD;
    const u16* Vg = Vt + (size_t)(kvh * HD) * S;
    u16* Pb = &Pl[w * 1024];

    bf16x8 qfA[4], qfB[4];
    {
        const u16* Qg = QK + h * HD;
        const size_t qrA = (size_t)(q0A + w * 16 + r16) * LDQ;
        const size_t qrB = (size_t)(q0B + w * 16 + r16) * LDQ;
#pragma unroll
        for (int kg = 0; kg < 4; ++kg) {
            qfA[kg] = *(const bf16x8*)&Qg[qrA + kg * 32 + g4 * 8];
            qfB[kg] = *(const bf16x8*)&Qg[qrB + kg * 32 + g4 * 8];
        }
    }

    f32x4 accA[8], accB[8];
    float mA = -3.0e38f, lA = 0.f, mB = -3.0e38f, lB = 0.f;
#pragma unroll
    for (int i = 0; i < 8; ++i) { accA[i] = f32x4{0,0,0,0}; accB[i] = f32x4{0,0,0,0}; }

    // stage KV tile tk into buffer b, source pre-swizzled (slot ^= row&7)
    auto stage = [&](int tk, int b) {
        const int kv0 = tk * 64;
#pragma unroll
        for (int i = 0; i < 4; ++i) {   // K: 64 rows x 256B (16 slots/row)
            int c = i * 256 + t;
            int r = c >> 4, s = (c & 15) ^ (r & 7);
            gload_lds16(Kg + (size_t)(kv0 + r) * LDQ + (s << 3),
                        &Kl[b][0] + ((i * 256 + w * 64) << 3));
        }
#pragma unroll
        for (int i = 0; i < 4; ++i) {   // Vt: 128 rows x 128B (8 slots/row)
            int c = i * 256 + t;
            int r = c >> 3, s = (c & 7) ^ (r & 7);
            gload_lds16(Vg + (size_t)r * S + kv0 + (s << 3),
                        &Vl[b][0] + ((i * 256 + w * 64) << 3));
        }
    };

    auto compute = [&](f32x4 (&acco)[8], float& mrun, float& lrun,
                       const bf16x8 (&qf)[4], int q0, int tk, bool maskit, int b) {
        const int kv0 = tk * 64;
        const u16* Kb = &Kl[b][0];
        const u16* Vb = &Vl[b][0];

        // swapped QK^T: D[kv][q]; lane owns q = r16, kv = ni*16 + g4*4 + j
        f32x4 sc[4];
#pragma unroll
        for (int ni = 0; ni < 4; ++ni) sc[ni] = f32x4{0,0,0,0};
        __builtin_amdgcn_s_setprio(1);
#pragma unroll
        for (int kg = 0; kg < 4; ++kg) {
#pragma unroll
            for (int ni = 0; ni < 4; ++ni) {
                int row = ni * 16 + r16;
                int bb = (row * 256 + kg * 64 + g4 * 16) ^ ((row & 7) << 4);
                bf16x8 kf = *(const bf16x8*)((const char*)Kb + bb);
                mfma16(sc[ni], kf, qf[kg]);   // K as A-operand, Q as B-operand
            }
        }
        __builtin_amdgcn_s_setprio(0);

        const int qg = q0 + (w << 4) + r16;   // this lane's q row
        if (maskit) {
#pragma unroll
            for (int ni = 0; ni < 4; ++ni)
#pragma unroll
                for (int j = 0; j < 4; ++j)
                    if (kv0 + ni * 16 + g4 * 4 + j > qg) sc[ni][j] = -3.0e38f;
        }

        // row max: in-lane tree over 16 regs + 2 shfl_xor
        float v = fmaxf(fmaxf(fmaxf(sc[0][0], sc[0][1]), fmaxf(sc[0][2], sc[0][3])),
                        fmaxf(fmaxf(sc[1][0], sc[1][1]), fmaxf(sc[1][2], sc[1][3])));
        v = fmaxf(v, fmaxf(fmaxf(fmaxf(sc[2][0], sc[2][1]), fmaxf(sc[2][2], sc[2][3])),
                           fmaxf(fmaxf(sc[3][0], sc[3][1]), fmaxf(sc[3][2], sc[3][3]))));
        v = fmaxf(v, __shfl_xor(v, 16));
        v = fmaxf(v, __shfl_xor(v, 32));

        float facl = 1.f;
        if (__any(v > mrun + 11.5f)) {        // defer-max (T13)
            float nm = fmaxf(mrun, v);
            facl = exp2f(mrun - nm);
            mrun = nm;
            float fj[4];
#pragma unroll
            for (int j = 0; j < 4; ++j) fj[j] = __shfl(facl, g4 * 4 + j, 16);
#pragma unroll
            for (int i = 0; i < 8; ++i)
#pragma unroll
                for (int j = 0; j < 4; ++j) acco[i][j] *= fj[j];
        }
#pragma unroll
        for (int ni = 0; ni < 4; ++ni)
#pragma unroll
            for (int j = 0; j < 4; ++j) sc[ni][j] = exp2f(sc[ni][j] - mrun);

        // row sum: in-lane 15 adds + 2 shfl_xor
        float s2 = ((sc[0][0] + sc[0][1]) + (sc[0][2] + sc[0][3]))
                 + ((sc[1][0] + sc[1][1]) + (sc[1][2] + sc[1][3]))
                 + ((sc[2][0] + sc[2][1]) + (sc[2][2] + sc[2][3]))
                 + ((sc[3][0] + sc[3][1]) + (sc[3][2] + sc[3][3]));
        s2 += __shfl_xor(s2, 16);
        s2 += __shfl_xor(s2, 32);
        lrun = lrun * facl + s2;

        // P transposed -> per-wave LDS [q=r16][kv], 8 packed u32 stores
        {
            char* pp = (char*)Pb;
            const int swz = (r16 & 7) << 4;
            const int rowb = r16 * 128;
#pragma unroll
            for (int ti = 0; ti < 4; ++ti) {
                unsigned r01 = pk2bf(sc[ti][0], sc[ti][1]);
                unsigned r23 = pk2bf(sc[ti][2], sc[ti][3]);
                const int colb = (ti * 16 + g4 * 4) << 1;
                *(unsigned*)(pp + ((rowb + colb) ^ swz))     = r01;
                *(unsigned*)(pp + ((rowb + colb + 4) ^ swz)) = r23;
            }
        }
        asm volatile("s_waitcnt lgkmcnt(0)" ::: "memory");
        __builtin_amdgcn_sched_barrier(0);

        // PV (unchanged R6 path): A = P[q][kv] frags, B = V^T frags
        int pb0 = (r16 * 128 + g4 * 16) ^ ((r16 & 7) << 4);
        bf16x8 pf0 = *(const bf16x8*)((const char*)Pb + pb0);
        bf16x8 pf1 = *(const bf16x8*)((const char*)Pb + (pb0 ^ 64));
        __builtin_amdgcn_s_setprio(1);
#pragma unroll
        for (int ni = 0; ni < 8; ++ni) {
            int row = ni * 16 + r16;
            int bb = (row * 128 + g4 * 16) ^ ((row & 7) << 4);
            bf16x8 v0 = *(const bf16x8*)((const char*)Vb + bb);
            mfma16(acco[ni], pf0, v0);
            bf16x8 v1 = *(const bf16x8*)((const char*)Vb + (bb ^ 64));
            mfma16(acco[ni], pf1, v1);
        }
        __builtin_amdgcn_s_setprio(0);
    };

    auto epilogue = [&](f32x4 (&acco)[8], float lrun, int q0) {
        float rlr = 1.0f / lrun;
        float rl[4];
#pragma unroll
        for (int j = 0; j < 4; ++j) rl[j] = __shfl(rlr, g4 * 4 + j, 16);
#pragma unroll
        for (int ni = 0; ni < 8; ++ni)
#pragma unroll
            for (int j = 0; j < 4; ++j) {
                const int qg = q0 + w * 16 + g4 * 4 + j;
                O[(size_t)qg * DM + h * HD + ni * 16 + r16] = f2bf(acco[ni][j] * rl[j]);
            }
    };

    stage(0, 0);
    asm volatile("s_waitcnt vmcnt(0)" ::: "memory");
    __syncthreads();
    int buf = 0;

    for (int tk = 0; tk < ntB; ++tk) {
        if (tk + 1 < ntB) stage(tk + 1, buf ^ 1);
        compute(accB, mB, lB, qfB, q0B, tk, tk == ntB - 1, buf);
        if (tk < ntA) compute(accA, mA, lA, qfA, q0A, tk, tk == ntA - 1, buf);
        asm volatile("s_waitcnt vmcnt(0)" ::: "memory");
        __syncthreads();
        buf ^= 1;
    }
    epilogue(accA, lA, q0A);
    epilogue(accB, lB, q0B);
}

// ---------------- launch ----------------
extern "C" void kernel_launch(void* const* d_in, const int* in_sizes, int n_in,
                              void* d_out, int out_size, void* d_ws, size_t ws_size,
                              hipStream_t stream) {
    const float* X  = (const float*)d_in[0];
    // d_in[1] = position_ids (arange(S) by construction)
    const float* Wq = (const float*)d_in[2];
    const float* Wk = (const float*)d_in[3];
    const float* Wv = (const float*)d_in[4];
    const float* Wo = (const float*)d_in[5];

    char* ws = (char*)d_ws;
    u16*    Xbf  = (u16*)(ws + 0);            // 2048x4096 bf16 = 16,777,216
    u16*    Wqkv = (u16*)(ws + 16777216);     // 6144x4096 bf16 = 50,331,648
    u16*    Wobf = (u16*)(ws + 67108864);     // 4096x4096 bf16 = 33,554,432
    u16*    QKb  = (u16*)(ws + 100663296);    // 2048x5120 bf16 = 20,971,520
    u16*    Vtbf = (u16*)(ws + 121634816);    // 1024x2048 bf16 =  4,194,304 (V^T)
    u16*    Obf  = (u16*)(ws + 125829120);    // 2048x4096 bf16 = 16,777,216
    float2* tbl  = (float2*)(ws + 142606336); // 2048x64 float2 =  1,048,576
    // split-K partials (2 x 2048x4096 f32 = 67,108,864) reuse [0, 67108864):
    // Xbf and Wqkv are dead once gemm_qkv has run (before the O-projection).
    float*  part = (float*)(ws + 0);
    if (ws_size < 143654912ull) return;

    dim3 blk(256);

    cvt_all<<<2048, blk, 0, stream>>>(X, Wq, Wk, Wv, Wo, (u16*)ws);
    rope_table_kernel<<<(S * 64 + 255) / 256, blk, 0, stream>>>(tbl);

    // fused QKV projection: m97 128^2 + T2 swizzle, grid 48x16 = 768 blocks (3/CU)
    gemm_qkv<<<dim3(48, 16), blk, 0, stream>>>(Xbf, Wqkv, QKb, Vtbf);

    // fused RoPE over Q+K heads; Q folds in log2(e)*HD^-0.5 (exp2-domain softmax)
    rope2_kernel<<<(S * 40 * 64 + 255) / 256, blk, 0, stream>>>(
        QKb, tbl, 0.08838834764831845f * 1.4426950408889634f);

    // attention: swapped-QK^T in-register softmax, merged pairs, grid (16,32)
    attn_fwd<<<dim3(16, NH), blk, 0, stream>>>(QKb, Vtbf, Obf);

    // output projection, split-K=2: grid (32,16,2) = 1024 blocks (4/CU),
    // f32 partials -> add2 reduce into d_out
    gemm_bt<2><<<dim3(32, 16, 2), blk, 0, stream>>>(
        Obf, Wobf, part, S, DM, DM, DM, DM, DM);
    add2_kernel<<<2048, blk, 0, stream>>>(part, part + (size_t)S * DM,
                                          (float*)d_out, S * DM / 4);
}

// Round 15
// 327.553 us; speedup vs baseline: 1.2571x; 1.0161x over previous
//
#include <hip/hip_runtime.h>
#include <stdint.h>

typedef unsigned short u16;
typedef __attribute__((ext_vector_type(4))) float f32x4;
typedef __attribute__((ext_vector_type(8))) short bf16x8;

static constexpr int S   = 2048;
static constexpr int DM  = 4096;  // model dim
static constexpr int NH  = 32;    // query heads
static constexpr int NKV = 8;     // kv heads
static constexpr int HD  = 128;   // head dim
static constexpr int LDQ = 5120;  // QK buffer row stride (Q 4096 | K 1024)

__device__ __forceinline__ u16 f2bf(float f) {
    union { float f; unsigned u; } v; v.f = f;
    return (u16)((v.u + 0x7FFFu + ((v.u >> 16) & 1u)) >> 16);
}
__device__ __forceinline__ float bf2f(u16 h) {
    union { unsigned u; float f; } v; v.u = ((unsigned)h) << 16;
    return v.f;
}
// pack 2 f32 -> 2 bf16 in one u32 (lo = first arg). T12 primitive.
__device__ __forceinline__ unsigned pk2bf(float lo, float hi) {
    unsigned r;
    asm("v_cvt_pk_bf16_f32 %0, %1, %2" : "=v"(r) : "v"(lo), "v"(hi));
    return r;
}

__device__ __forceinline__ void mfma16(f32x4& d, bf16x8 a, bf16x8 b) {
    asm("v_mfma_f32_16x16x32_bf16 %0, %1, %2, %0" : "+v"(d) : "v"(a), "v"(b));
}

// async global->LDS, 16B/lane. LDS base is wave-uniform; HW adds lane*16.
__device__ __forceinline__ void gload_lds16(const u16* g, u16* lds) {
    __builtin_amdgcn_global_load_lds((__attribute__((address_space(1))) void*)g,
                                     (__attribute__((address_space(3))) void*)lds,
                                     16, 0, 0);
}

// ---------------- fused fp32 -> bf16 convert: X | Wq | Wk | Wv | Wo ----------------
__global__ __launch_bounds__(256) void cvt_all(const float* __restrict__ X,
                                               const float* __restrict__ Wq,
                                               const float* __restrict__ Wk,
                                               const float* __restrict__ Wv,
                                               const float* __restrict__ Wo,
                                               u16* __restrict__ out) {
    const int n4 = 12582912;  // total float4 count
    int i = blockIdx.x * blockDim.x + threadIdx.x;
    int stride = gridDim.x * blockDim.x;
    for (; i < n4; i += stride) {
        float4 v;
        if (i < 2097152)       v = ((const float4*)X)[i];
        else if (i < 6291456)  v = ((const float4*)Wq)[i - 2097152];
        else if (i < 7340032)  v = ((const float4*)Wk)[i - 6291456];
        else if (i < 8388608)  v = ((const float4*)Wv)[i - 7340032];
        else                   v = ((const float4*)Wo)[i - 8388608];
        ushort4 o;
        o.x = f2bf(v.x); o.y = f2bf(v.y); o.z = f2bf(v.z); o.w = f2bf(v.w);
        ((ushort4*)out)[i] = o;
    }
}

// ---------------- split-K reduce: out = bf16(a) + bf16(b) -> f32 ----------------
__global__ __launch_bounds__(256) void add2bf_kernel(const u16* __restrict__ a,
                                                     const u16* __restrict__ b,
                                                     float* __restrict__ o, int n4) {
    int i = blockIdx.x * blockDim.x + threadIdx.x;
    int st = gridDim.x * blockDim.x;
    for (; i < n4; i += st) {
        ushort4 x = ((const ushort4*)a)[i];
        ushort4 y = ((const ushort4*)b)[i];
        float4 r;
        r.x = bf2f(x.x) + bf2f(y.x);
        r.y = bf2f(x.y) + bf2f(y.y);
        r.z = bf2f(x.z) + bf2f(y.z);
        r.w = bf2f(x.w) + bf2f(y.w);
        ((float4*)o)[i] = r;
    }
}

// ---------------- RoPE cos/sin table ----------------
__global__ __launch_bounds__(256) void rope_table_kernel(float2* __restrict__ tbl) {
    int i = blockIdx.x * blockDim.x + threadIdx.x;
    if (i >= S * 64) return;
    int p = i >> 6, j = i & 63;
    float inv = powf(10000.0f, -(float)j / 64.0f);
    float a = (float)p * inv;
    tbl[i] = make_float2(cosf(a), sinf(a));
}

// ---------------- fused RoPE: Q heads (scale) + K heads, in-place on QKb ----------------
__global__ __launch_bounds__(256) void rope2_kernel(u16* __restrict__ X,
                                                    const float2* __restrict__ tbl,
                                                    float qscale) {
    int i = blockIdx.x * blockDim.x + threadIdx.x;
    const int total = S * 40 * 64;   // 32 Q heads + 8 K heads
    if (i >= total) return;
    int dd = i & 63;
    int t2 = i >> 6;
    int hh = t2 % 40;
    int s  = t2 / 40;
    size_t base;
    float scale;
    if (hh < 32) { base = (size_t)s * LDQ + hh * HD + dd;               scale = qscale; }
    else         { base = (size_t)s * LDQ + 4096 + (hh - 32) * HD + dd; scale = 1.0f;   }
    float x1 = bf2f(X[base]);
    float x2 = bf2f(X[base + 64]);
    float2 cs = tbl[(s << 6) + dd];
    X[base]      = f2bf((x1 * cs.x - x2 * cs.y) * scale);
    X[base + 64] = f2bf((x2 * cs.x + x1 * cs.y) * scale);
}

// ============== m97-structure 128x128 GEMM (4 waves, BK=64, 2-barrier) ==============
// SPLITK>1: blockIdx.z picks a K-slice of length K/SPLITK; bf16 partials are
// written to Cp + z*M*ldc (reduce with add2bf_kernel). SPLITK==1: f32 to C.
template<int SPLITK>
__global__ __launch_bounds__(256)
void gemm_bt(const u16* __restrict__ A, const u16* __restrict__ Bt,
             float* __restrict__ C, u16* __restrict__ Cp,
             int M, int N, int K, int lda, int ldb, int ldc) {
    __shared__ u16 Al[128 * 64];
    __shared__ u16 Bl[128 * 64];
    const int t = threadIdx.x;
    const int w = t >> 6, l = t & 63;
    const int r16 = l & 15, g4 = l >> 4;
    const int m0 = blockIdx.y * 128, n0 = blockIdx.x * 128;
    const int wr = (w >> 1) * 64, wc = (w & 1) * 64;

    const int Kper = K / SPLITK;
    const int k0 = (SPLITK > 1) ? blockIdx.z * Kper : 0;
    if (SPLITK > 1) Cp += (size_t)blockIdx.z * M * ldc;

    f32x4 acc[4][4];
#pragma unroll
    for (int i = 0; i < 4; ++i)
#pragma unroll
        for (int j = 0; j < 4; ++j) acc[i][j] = f32x4{0.f, 0.f, 0.f, 0.f};

    for (int kt = k0; kt < k0 + Kper; kt += 64) {
#pragma unroll
        for (int i = 0; i < 4; ++i) {
            int c = i * 256 + t;
            int r = c >> 3, s = (c & 7) ^ (r & 7);
            gload_lds16(A + (size_t)(m0 + r) * lda + kt + (s << 3),
                        Al + ((i * 256 + w * 64) << 3));
        }
#pragma unroll
        for (int i = 0; i < 4; ++i) {
            int c = i * 256 + t;
            int r = c >> 3, s = (c & 7) ^ (r & 7);
            gload_lds16(Bt + (size_t)(n0 + r) * ldb + kt + (s << 3),
                        Bl + ((i * 256 + w * 64) << 3));
        }
        asm volatile("s_waitcnt vmcnt(0)" ::: "memory");
        __syncthreads();

#pragma unroll
        for (int kk = 0; kk < 2; ++kk) {
            bf16x8 af[4], bfr[4];
#pragma unroll
            for (int mi = 0; mi < 4; ++mi) {
                int r = wr + mi * 16 + r16;
                af[mi] = *(const bf16x8*)((const char*)Al +
                          ((r * 128 + kk * 64 + g4 * 16) ^ ((r & 7) << 4)));
            }
#pragma unroll
            for (int ni = 0; ni < 4; ++ni) {
                int r = wc + ni * 16 + r16;
                bfr[ni] = *(const bf16x8*)((const char*)Bl +
                           ((r * 128 + kk * 64 + g4 * 16) ^ ((r & 7) << 4)));
            }
#pragma unroll
            for (int mi = 0; mi < 4; ++mi)
#pragma unroll
                for (int ni = 0; ni < 4; ++ni)
                    mfma16(acc[mi][ni], af[mi], bfr[ni]);
        }
        __syncthreads();
    }

    const int rb = g4 * 4;
#pragma unroll
    for (int mi = 0; mi < 4; ++mi)
#pragma unroll
        for (int ni = 0; ni < 4; ++ni) {
            const int n = n0 + wc + ni * 16 + r16;
            const int mbase = m0 + wr + mi * 16 + rb;
            if constexpr (SPLITK > 1) {
#pragma unroll
                for (int j = 0; j < 4; ++j)
                    Cp[(size_t)(mbase + j) * ldc + n] = f2bf(acc[mi][ni][j]);
            } else {
#pragma unroll
                for (int j = 0; j < 4; ++j)
                    C[(size_t)(mbase + j) * ldc + n] = acc[mi][ni][j];
            }
        }
}

// ---------------- fused QKV GEMM: X[2048][4096] * Wqkv[6144][4096]^T ----------------
__global__ __launch_bounds__(256)
void gemm_qkv(const u16* __restrict__ A, const u16* __restrict__ Bt,
              u16* __restrict__ Cqk, u16* __restrict__ Vt) {
    __shared__ u16 Al[128 * 64];
    __shared__ u16 Bl[128 * 64];
    const int t = threadIdx.x;
    const int w = t >> 6, l = t & 63;
    const int r16 = l & 15, g4 = l >> 4;
    const int m0 = blockIdx.y * 128, n0 = blockIdx.x * 128;
    const int wr = (w >> 1) * 64, wc = (w & 1) * 64;

    f32x4 acc[4][4];
#pragma unroll
    for (int i = 0; i < 4; ++i)
#pragma unroll
        for (int j = 0; j < 4; ++j) acc[i][j] = f32x4{0.f, 0.f, 0.f, 0.f};

    for (int kt = 0; kt < DM; kt += 64) {
#pragma unroll
        for (int i = 0; i < 4; ++i) {
            int c = i * 256 + t;
            int r = c >> 3, s = (c & 7) ^ (r & 7);
            gload_lds16(A + (size_t)(m0 + r) * DM + kt + (s << 3),
                        Al + ((i * 256 + w * 64) << 3));
        }
#pragma unroll
        for (int i = 0; i < 4; ++i) {
            int c = i * 256 + t;
            int r = c >> 3, s = (c & 7) ^ (r & 7);
            gload_lds16(Bt + (size_t)(n0 + r) * DM + kt + (s << 3),
                        Bl + ((i * 256 + w * 64) << 3));
        }
        asm volatile("s_waitcnt vmcnt(0)" ::: "memory");
        __syncthreads();

#pragma unroll
        for (int kk = 0; kk < 2; ++kk) {
            bf16x8 af[4], bfr[4];
#pragma unroll
            for (int mi = 0; mi < 4; ++mi) {
                int r = wr + mi * 16 + r16;
                af[mi] = *(const bf16x8*)((const char*)Al +
                          ((r * 128 + kk * 64 + g4 * 16) ^ ((r & 7) << 4)));
            }
#pragma unroll
            for (int ni = 0; ni < 4; ++ni) {
                int r = wc + ni * 16 + r16;
                bfr[ni] = *(const bf16x8*)((const char*)Bl +
                           ((r * 128 + kk * 64 + g4 * 16) ^ ((r & 7) << 4)));
            }
#pragma unroll
            for (int mi = 0; mi < 4; ++mi)
#pragma unroll
                for (int ni = 0; ni < 4; ++ni)
                    mfma16(acc[mi][ni], af[mi], bfr[ni]);
        }
        __syncthreads();
    }

    const int rb = g4 * 4;
    if (n0 < 5120) {  // Q|K region, row-major
#pragma unroll
        for (int mi = 0; mi < 4; ++mi)
#pragma unroll
            for (int ni = 0; ni < 4; ++ni) {
                const int n = n0 + wc + ni * 16 + r16;
                const int mbase = m0 + wr + mi * 16 + rb;
#pragma unroll
                for (int j = 0; j < 4; ++j)
                    Cqk[(size_t)(mbase + j) * LDQ + n] = f2bf(acc[mi][ni][j]);
            }
    } else {          // V region, transposed into Vt[1024][2048]
#pragma unroll
        for (int mi = 0; mi < 4; ++mi)
#pragma unroll
            for (int ni = 0; ni < 4; ++ni) {
                const int n = n0 + wc + ni * 16 + r16 - 5120;
                const int mbase = m0 + wr + mi * 16 + rb;
                ushort4 v4;
                v4.x = f2bf(acc[mi][ni][0]); v4.y = f2bf(acc[mi][ni][1]);
                v4.z = f2bf(acc[mi][ni][2]); v4.w = f2bf(acc[mi][ni][3]);
                *(ushort4*)&Vt[(size_t)n * S + mbase] = v4;
            }
    }
}

// ---------------- causal GQA flash attention (4 waves, merged pairs, swapped QK^T) ----------------
// grid (16, 32): block p handles q-tiles p and 31-p; one KV stage serves both
// computes (33 tile-computes per block, balanced). SWAPPED QK^T: mfma(K, Q) gives
// D[kv][q] -- each lane owns ONE q-row (q = lane&15) with all 64 kv in registers,
// so row max/sum = in-lane tree + 2 shfl_xor. mrun/lrun are per-lane scalars;
// rescale factors broadcast by 4 width-16 shuffles on grow only. P written
// transposed into the per-wave [q][kv] LDS buffer the PV path consumes.
// exp2-domain softmax, defer-max. All LDS XOR-swizzled. 72KB LDS.
__global__ __launch_bounds__(256, 2)
void attn_fwd(const u16* __restrict__ QK, const u16* __restrict__ Vt,
              u16* __restrict__ O) {
    __shared__ u16 Kl[2][64 * 128];   // 2 x 16KB
    __shared__ u16 Vl[2][128 * 64];   // 2 x 16KB
    __shared__ u16 Pl[4 * 1024];      // 8KB, per-wave 2KB

    const int t = threadIdx.x;
    const int w = t >> 6, l = t & 63;
    const int r16 = l & 15, g4 = l >> 4;
    const int h = blockIdx.y;
    const int kvh = h >> 2;
    const int p = blockIdx.x;                 // 0..15
    const int q0A = p * 64, q0B = (31 - p) * 64;
    const int ntA = p + 1, ntB = 32 - p;      // ntA <= ntB

    const u16* Kg = QK + 4096 + kvh * HD;
    const u16* Vg = Vt + (size_t)(kvh * HD) * S;
    u16* Pb = &Pl[w * 1024];

    bf16x8 qfA[4], qfB[4];
    {
        const u16* Qg = QK + h * HD;
        const size_t qrA = (size_t)(q0A + w * 16 + r16) * LDQ;
        const size_t qrB = (size_t)(q0B + w * 16 + r16) * LDQ;
#pragma unroll
        for (int kg = 0; kg < 4; ++kg) {
            qfA[kg] = *(const bf16x8*)&Qg[qrA + kg * 32 + g4 * 8];
            qfB[kg] = *(const bf16x8*)&Qg[qrB + kg * 32 + g4 * 8];
        }
    }

    f32x4 accA[8], accB[8];
    float mA = -3.0e38f, lA = 0.f, mB = -3.0e38f, lB = 0.f;
#pragma unroll
    for (int i = 0; i < 8; ++i) { accA[i] = f32x4{0,0,0,0}; accB[i] = f32x4{0,0,0,0}; }

    // stage KV tile tk into buffer b, source pre-swizzled (slot ^= row&7)
    auto stage = [&](int tk, int b) {
        const int kv0 = tk * 64;
#pragma unroll
        for (int i = 0; i < 4; ++i) {   // K: 64 rows x 256B (16 slots/row)
            int c = i * 256 + t;
            int r = c >> 4, s = (c & 15) ^ (r & 7);
            gload_lds16(Kg + (size_t)(kv0 + r) * LDQ + (s << 3),
                        &Kl[b][0] + ((i * 256 + w * 64) << 3));
        }
#pragma unroll
        for (int i = 0; i < 4; ++i) {   // Vt: 128 rows x 128B (8 slots/row)
            int c = i * 256 + t;
            int r = c >> 3, s = (c & 7) ^ (r & 7);
            gload_lds16(Vg + (size_t)r * S + kv0 + (s << 3),
                        &Vl[b][0] + ((i * 256 + w * 64) << 3));
        }
    };

    auto compute = [&](f32x4 (&acco)[8], float& mrun, float& lrun,
                       const bf16x8 (&qf)[4], int q0, int tk, bool maskit, int b) {
        const int kv0 = tk * 64;
        const u16* Kb = &Kl[b][0];
        const u16* Vb = &Vl[b][0];

        // swapped QK^T: D[kv][q]; lane owns q = r16, kv = ni*16 + g4*4 + j
        f32x4 sc[4];
#pragma unroll
        for (int ni = 0; ni < 4; ++ni) sc[ni] = f32x4{0,0,0,0};
        __builtin_amdgcn_s_setprio(1);
#pragma unroll
        for (int kg = 0; kg < 4; ++kg) {
#pragma unroll
            for (int ni = 0; ni < 4; ++ni) {
                int row = ni * 16 + r16;
                int bb = (row * 256 + kg * 64 + g4 * 16) ^ ((row & 7) << 4);
                bf16x8 kf = *(const bf16x8*)((const char*)Kb + bb);
                mfma16(sc[ni], kf, qf[kg]);   // K as A-operand, Q as B-operand
            }
        }
        __builtin_amdgcn_s_setprio(0);

        const int qg = q0 + (w << 4) + r16;   // this lane's q row
        if (maskit) {
#pragma unroll
            for (int ni = 0; ni < 4; ++ni)
#pragma unroll
                for (int j = 0; j < 4; ++j)
                    if (kv0 + ni * 16 + g4 * 4 + j > qg) sc[ni][j] = -3.0e38f;
        }

        // row max: in-lane tree over 16 regs + 2 shfl_xor
        float v = fmaxf(fmaxf(fmaxf(sc[0][0], sc[0][1]), fmaxf(sc[0][2], sc[0][3])),
                        fmaxf(fmaxf(sc[1][0], sc[1][1]), fmaxf(sc[1][2], sc[1][3])));
        v = fmaxf(v, fmaxf(fmaxf(fmaxf(sc[2][0], sc[2][1]), fmaxf(sc[2][2], sc[2][3])),
                           fmaxf(fmaxf(sc[3][0], sc[3][1]), fmaxf(sc[3][2], sc[3][3]))));
        v = fmaxf(v, __shfl_xor(v, 16));
        v = fmaxf(v, __shfl_xor(v, 32));

        float facl = 1.f;
        if (__any(v > mrun + 11.5f)) {        // defer-max (T13)
            float nm = fmaxf(mrun, v);
            facl = exp2f(mrun - nm);
            mrun = nm;
            float fj[4];
#pragma unroll
            for (int j = 0; j < 4; ++j) fj[j] = __shfl(facl, g4 * 4 + j, 16);
#pragma unroll
            for (int i = 0; i < 8; ++i)
#pragma unroll
                for (int j = 0; j < 4; ++j) acco[i][j] *= fj[j];
        }
#pragma unroll
        for (int ni = 0; ni < 4; ++ni)
#pragma unroll
            for (int j = 0; j < 4; ++j) sc[ni][j] = exp2f(sc[ni][j] - mrun);

        // row sum: in-lane 15 adds + 2 shfl_xor
        float s2 = ((sc[0][0] + sc[0][1]) + (sc[0][2] + sc[0][3]))
                 + ((sc[1][0] + sc[1][1]) + (sc[1][2] + sc[1][3]))
                 + ((sc[2][0] + sc[2][1]) + (sc[2][2] + sc[2][3]))
                 + ((sc[3][0] + sc[3][1]) + (sc[3][2] + sc[3][3]));
        s2 += __shfl_xor(s2, 16);
        s2 += __shfl_xor(s2, 32);
        lrun = lrun * facl + s2;

        // P transposed -> per-wave LDS [q=r16][kv], 8 packed u32 stores
        {
            char* pp = (char*)Pb;
            const int swz = (r16 & 7) << 4;
            const int rowb = r16 * 128;
#pragma unroll
            for (int ti = 0; ti < 4; ++ti) {
                unsigned r01 = pk2bf(sc[ti][0], sc[ti][1]);
                unsigned r23 = pk2bf(sc[ti][2], sc[ti][3]);
                const int colb = (ti * 16 + g4 * 4) << 1;
                *(unsigned*)(pp + ((rowb + colb) ^ swz))     = r01;
                *(unsigned*)(pp + ((rowb + colb + 4) ^ swz)) = r23;
            }
        }
        asm volatile("s_waitcnt lgkmcnt(0)" ::: "memory");
        __builtin_amdgcn_sched_barrier(0);

        // PV: A = P[q][kv] frags, B = V^T frags
        int pb0 = (r16 * 128 + g4 * 16) ^ ((r16 & 7) << 4);
        bf16x8 pf0 = *(const bf16x8*)((const char*)Pb + pb0);
        bf16x8 pf1 = *(const bf16x8*)((const char*)Pb + (pb0 ^ 64));
        __builtin_amdgcn_s_setprio(1);
#pragma unroll
        for (int ni = 0; ni < 8; ++ni) {
            int row = ni * 16 + r16;
            int bb = (row * 128 + g4 * 16) ^ ((row & 7) << 4);
            bf16x8 v0 = *(const bf16x8*)((const char*)Vb + bb);
            mfma16(acco[ni], pf0, v0);
            bf16x8 v1 = *(const bf16x8*)((const char*)Vb + (bb ^ 64));
            mfma16(acco[ni], pf1, v1);
        }
        __builtin_amdgcn_s_setprio(0);
    };

    auto epilogue = [&](f32x4 (&acco)[8], float lrun, int q0) {
        float rlr = 1.0f / lrun;
        float rl[4];
#pragma unroll
        for (int j = 0; j < 4; ++j) rl[j] = __shfl(rlr, g4 * 4 + j, 16);
#pragma unroll
        for (int ni = 0; ni < 8; ++ni)
#pragma unroll
            for (int j = 0; j < 4; ++j) {
                const int qg = q0 + w * 16 + g4 * 4 + j;
                O[(size_t)qg * DM + h * HD + ni * 16 + r16] = f2bf(acco[ni][j] * rl[j]);
            }
    };

    stage(0, 0);
    asm volatile("s_waitcnt vmcnt(0)" ::: "memory");
    __syncthreads();
    int buf = 0;

    for (int tk = 0; tk < ntB; ++tk) {
        if (tk + 1 < ntB) stage(tk + 1, buf ^ 1);
        compute(accB, mB, lB, qfB, q0B, tk, tk == ntB - 1, buf);
        if (tk < ntA) compute(accA, mA, lA, qfA, q0A, tk, tk == ntA - 1, buf);
        asm volatile("s_waitcnt vmcnt(0)" ::: "memory");
        __syncthreads();
        buf ^= 1;
    }
    epilogue(accA, lA, q0A);
    epilogue(accB, lB, q0B);
}

// ---------------- launch ----------------
extern "C" void kernel_launch(void* const* d_in, const int* in_sizes, int n_in,
                              void* d_out, int out_size, void* d_ws, size_t ws_size,
                              hipStream_t stream) {
    const float* X  = (const float*)d_in[0];
    // d_in[1] = position_ids (arange(S) by construction)
    const float* Wq = (const float*)d_in[2];
    const float* Wk = (const float*)d_in[3];
    const float* Wv = (const float*)d_in[4];
    const float* Wo = (const float*)d_in[5];

    char* ws = (char*)d_ws;
    u16*    Xbf  = (u16*)(ws + 0);            // 2048x4096 bf16 = 16,777,216
    u16*    Wqkv = (u16*)(ws + 16777216);     // 6144x4096 bf16 = 50,331,648
    u16*    Wobf = (u16*)(ws + 67108864);     // 4096x4096 bf16 = 33,554,432
    u16*    QKb  = (u16*)(ws + 100663296);    // 2048x5120 bf16 = 20,971,520
    u16*    Vtbf = (u16*)(ws + 121634816);    // 1024x2048 bf16 =  4,194,304 (V^T)
    u16*    Obf  = (u16*)(ws + 125829120);    // 2048x4096 bf16 = 16,777,216
    float2* tbl  = (float2*)(ws + 142606336); // 2048x64 float2 =  1,048,576
    // split-K bf16 partials (2 x 2048x4096 bf16 = 33,554,432) reuse [0, 33554432):
    // Xbf (and Wqkv) are dead once gemm_qkv has run (before the O-projection).
    u16*    part = (u16*)(ws + 0);
    if (ws_size < 143654912ull) return;

    dim3 blk(256);

    cvt_all<<<2048, blk, 0, stream>>>(X, Wq, Wk, Wv, Wo, (u16*)ws);
    rope_table_kernel<<<(S * 64 + 255) / 256, blk, 0, stream>>>(tbl);

    // fused QKV projection: m97 128^2 + T2 swizzle, grid 48x16 = 768 blocks (3/CU)
    gemm_qkv<<<dim3(48, 16), blk, 0, stream>>>(Xbf, Wqkv, QKb, Vtbf);

    // fused RoPE over Q+K heads; Q folds in log2(e)*HD^-0.5 (exp2-domain softmax)
    rope2_kernel<<<(S * 40 * 64 + 255) / 256, blk, 0, stream>>>(
        QKb, tbl, 0.08838834764831845f * 1.4426950408889634f);

    // attention: swapped-QK^T in-register softmax, merged pairs, grid (16,32)
    attn_fwd<<<dim3(16, NH), blk, 0, stream>>>(QKb, Vtbf, Obf);

    // output projection, split-K=2: grid (32,16,2) = 1024 blocks (4/CU),
    // bf16 partials -> add2bf reduce into f32 d_out
    gemm_bt<2><<<dim3(32, 16, 2), blk, 0, stream>>>(
        Obf, Wobf, nullptr, part, S, DM, DM, DM, DM, DM);
    add2bf_kernel<<<2048, blk, 0, stream>>>(part, part + (size_t)S * DM,
                                            (float*)d_out, S * DM / 4);
}